// Round 8
// baseline (294.150 us; speedup 1.0000x reference)
//
#include <hip/hip_runtime.h>
#include <hip/hip_bf16.h>

#define BN_EPS 1e-5f
#define NBLK_STAT 256
#define CB_SHIFT 9            // 512 nodes per coarse bucket
#define CB_NODES 512
#define P1_CHUNK 8192

typedef __attribute__((ext_vector_type(8))) short short8;
typedef __attribute__((ext_vector_type(4))) float f32x4;

__device__ __forceinline__ ushort f2bf(float x) {
    uint u = __float_as_uint(x);
    u += 0x7FFF + ((u >> 16) & 1);      // round-to-nearest-even
    return (ushort)(u >> 16);
}
__device__ __forceinline__ float bf2f(uint h) { return __uint_as_float(h << 16); }

__device__ __forceinline__ void unpack8(uint4 u, float* v) {
    v[0] = bf2f(u.x & 0xffffu); v[1] = bf2f(u.x >> 16);
    v[2] = bf2f(u.y & 0xffffu); v[3] = bf2f(u.y >> 16);
    v[4] = bf2f(u.z & 0xffffu); v[5] = bf2f(u.z >> 16);
    v[6] = bf2f(u.w & 0xffffu); v[7] = bf2f(u.w >> 16);
}

// ---------------- CSR build (bucketed, no per-node global atomics) ----------------

// coarse-bucket histogram of dst
__global__ __launch_bounds__(256) void k_degcb(const int* __restrict__ dst,
                                               int* __restrict__ cbcnt, int E, int ncb) {
    __shared__ int l[512];
    int t = threadIdx.x;
    for (int i = t; i < 512; i += 256) l[i] = 0;
    __syncthreads();
    int stride = gridDim.x * 256;
    for (int e = blockIdx.x * 256 + t; e < E; e += stride)
        atomicAdd(&l[dst[e] >> CB_SHIFT], 1);
    __syncthreads();
    for (int i = t; i < 512; i += 256)
        if (l[i]) atomicAdd(&cbcnt[i], l[i]);
}

// 1-block scan of bucket counts -> bucket bases + claim counters
__global__ __launch_bounds__(512) void k_scancb(const int* __restrict__ cbcnt,
                                                int* __restrict__ bbase,
                                                int* __restrict__ claim,
                                                int* __restrict__ rowptr,
                                                int ncb, int n, int E) {
    __shared__ int l[512];
    int t = threadIdx.x;
    int c = (t < ncb) ? cbcnt[t] : 0;
    l[t] = c;
    __syncthreads();
    for (int off = 1; off < 512; off <<= 1) {
        int v = l[t];
        int a = (t >= off) ? l[t - off] : 0;
        __syncthreads();
        l[t] = v + a;
        __syncthreads();
    }
    if (t < ncb) {
        int excl = l[t] - c;
        bbase[t] = excl;
        claim[t] = excl;
    }
    if (t == 0) {
        bbase[ncb] = E;
        rowptr[n] = E;
    }
}

// pass 1: scatter edges into coarse-bucket-grouped key array.
// key = (dst_local << 17) | src   (requires N <= 131072)
__global__ __launch_bounds__(256) void k_p1(const int* __restrict__ src,
                                            const int* __restrict__ dst,
                                            int* __restrict__ claim,
                                            uint* __restrict__ keys,
                                            int E, int ncb) {
    __shared__ int hist[512];
    __shared__ int wpos[512];
    int tid = threadIdx.x;
    int c0 = blockIdx.x * P1_CHUNK;
    for (int b = tid; b < 512; b += 256) hist[b] = 0;
    __syncthreads();
    for (int i = tid; i < P1_CHUNK; i += 256) {
        int e = c0 + i;
        if (e < E) atomicAdd(&hist[dst[e] >> CB_SHIFT], 1);
    }
    __syncthreads();
    for (int b = tid; b < 512; b += 256)
        wpos[b] = hist[b] ? atomicAdd(&claim[b], hist[b]) : 0;
    __syncthreads();
    for (int i = tid; i < P1_CHUNK; i += 256) {
        int e = c0 + i;
        if (e < E) {
            int d = dst[e];
            int b = d >> CB_SHIFT;
            uint key = ((uint)(d & (CB_NODES - 1)) << 17) | (uint)src[e];
            int slot = atomicAdd(&wpos[b], 1);
            keys[slot] = key;
        }
    }
}

// pass 2 per bucket: LDS hist -> local scan -> rowptr/dinv -> scatter col
__global__ __launch_bounds__(256) void k_build(const uint* __restrict__ keys,
                                               const int* __restrict__ bbase,
                                               int* __restrict__ rowptr,
                                               float* __restrict__ dinv,
                                               int* __restrict__ col, int n) {
    __shared__ int hist[CB_NODES];
    __shared__ int excl[CB_NODES];
    __shared__ int lpos[CB_NODES];
    __shared__ int ps[256];
    int t = threadIdx.x;
    int cb = blockIdx.x;
    int lo = bbase[cb], hi = bbase[cb + 1];
    for (int i = t; i < CB_NODES; i += 256) { hist[i] = 0; lpos[i] = 0; }
    __syncthreads();
    for (int j = lo + t; j < hi; j += 256) atomicAdd(&hist[keys[j] >> 17], 1);
    __syncthreads();
    ps[t] = hist[2 * t] + hist[2 * t + 1];
    __syncthreads();
    for (int off = 1; off < 256; off <<= 1) {
        int v = ps[t];
        int a = (t >= off) ? ps[t - off] : 0;
        __syncthreads();
        ps[t] = v + a;
        __syncthreads();
    }
    int base = (t == 0) ? 0 : ps[t - 1];
    excl[2 * t] = base;
    excl[2 * t + 1] = base + hist[2 * t];
    __syncthreads();
    for (int i = t; i < CB_NODES; i += 256) {
        int node = (cb << CB_SHIFT) + i;
        if (node < n) {
            rowptr[node] = lo + excl[i];
            dinv[node] = rsqrtf((float)hist[i] + 1.0f);
        }
    }
    __syncthreads();
    for (int j = lo + t; j < hi; j += 256) {
        uint key = keys[j];
        int nl = key >> 17;
        int p = lo + excl[nl] + atomicAdd(&lpos[nl], 1);
        col[p] = (int)(key & 0x1FFFFu);
    }
}

// ---------------- MFMA bf16 GEMM: C[n,OUT] = transform(A[n,K]) @ W[K,OUT] ----------------

__global__ __launch_bounds__(256) void k_gemm_mfma(
    const float* __restrict__ Af, const ushort* __restrict__ Ab,
    const float* __restrict__ Wg,
    ushort* __restrict__ Cb, float* __restrict__ Cf,
    const float* __restrict__ scale, const float* __restrict__ shift,
    const float* __restrict__ dinv,
    int n, int K, int OUT)
{
    __shared__ ushort As[64][40];   // [row][k]
    __shared__ ushort Wt[64][40];   // [col][k]
    const int row0 = blockIdx.x * 64;
    const int col0 = blockIdx.y * 64;
    const int tid = threadIdx.x;
    const int wv = tid >> 6;
    const int lane = tid & 63;
    const int fr = lane & 15;
    const int kb = lane >> 4;

    const int ar  = tid >> 2;
    const int akc = (tid & 3) << 3;
    const int wk  = tid >> 3;
    const int wcg = (tid & 7) << 3;

    f32x4 acc[4];
    acc[0] = acc[1] = acc[2] = acc[3] = (f32x4){0.f, 0.f, 0.f, 0.f};

    for (int k0 = 0; k0 < K; k0 += 32) {
        float v[8];
        int gr = row0 + ar;
        if (gr < n) {
            if (Af) {
                const float* ap = Af + (size_t)gr * K + k0 + akc;
                float4 x0 = *(const float4*)ap;
                float4 x1 = *(const float4*)(ap + 4);
                v[0] = x0.x; v[1] = x0.y; v[2] = x0.z; v[3] = x0.w;
                v[4] = x1.x; v[5] = x1.y; v[6] = x1.z; v[7] = x1.w;
            } else {
                uint4 u = *(const uint4*)(Ab + (size_t)gr * K + k0 + akc);
                unpack8(u, v);
            }
        } else {
            #pragma unroll
            for (int j = 0; j < 8; ++j) v[j] = 0.f;
        }
        if (scale) {
            #pragma unroll
            for (int j = 0; j < 8; ++j)
                v[j] = fmaxf(v[j] * scale[k0 + akc + j] + shift[k0 + akc + j], 0.f);
        }
        {
            uint4 w;
            w.x = (uint)f2bf(v[0]) | ((uint)f2bf(v[1]) << 16);
            w.y = (uint)f2bf(v[2]) | ((uint)f2bf(v[3]) << 16);
            w.z = (uint)f2bf(v[4]) | ((uint)f2bf(v[5]) << 16);
            w.w = (uint)f2bf(v[6]) | ((uint)f2bf(v[7]) << 16);
            *(uint4*)&As[ar][akc] = w;
        }
        {
            const float* wp = Wg + (size_t)(k0 + wk) * OUT + col0 + wcg;
            float4 y0 = *(const float4*)wp;
            float4 y1 = *(const float4*)(wp + 4);
            float wv8[8] = {y0.x, y0.y, y0.z, y0.w, y1.x, y1.y, y1.z, y1.w};
            #pragma unroll
            for (int j = 0; j < 8; ++j) Wt[wcg + j][wk] = f2bf(wv8[j]);
        }
        __syncthreads();
        short8 a = *(const short8*)&As[16 * wv + fr][kb << 3];
        #pragma unroll
        for (int ct = 0; ct < 4; ++ct) {
            short8 b = *(const short8*)&Wt[ct * 16 + fr][kb << 3];
            acc[ct] = __builtin_amdgcn_mfma_f32_16x16x32_bf16(a, b, acc[ct], 0, 0, 0);
        }
        __syncthreads();
    }

    #pragma unroll
    for (int r = 0; r < 4; ++r) {
        int gr = row0 + 16 * wv + (kb << 2) + r;
        if (gr >= n) continue;
        float dv = dinv ? dinv[gr] : 1.0f;
        #pragma unroll
        for (int ct = 0; ct < 4; ++ct) {
            float val = acc[ct][r] * dv;
            int gc = col0 + ct * 16 + fr;
            if (Cb) Cb[(size_t)gr * OUT + gc] = f2bf(val);
            else    Cf[(size_t)gr * OUT + gc] = val;
        }
    }
}

// ---------------- aggregation + fused BN partial stats (conv1/conv2) ----------------
// out[i] = dinv[i] * (Hs[i] + sum_{src} Hs[src]); Hs pre-scaled by dinv.
// Per-block: partial sum/sumsq of outputs (f32) -> part[bid], part[nblk+bid].

__global__ __launch_bounds__(256) void k_agg_st(
    const ushort* __restrict__ Hs, const float* __restrict__ dinv,
    const int* __restrict__ rowptr, const int* __restrict__ col,
    ushort* __restrict__ outp, float* __restrict__ part, int n, int nblk)
{
    int tid = threadIdx.x;
    int gt = blockIdx.x * 256 + tid;
    int lane = gt & 63;
    int sub = lane >> 3;
    int cg = (lane & 7) << 3;
    int node = (gt >> 6) * 8 + sub;
    float o[8] = {0.f, 0.f, 0.f, 0.f, 0.f, 0.f, 0.f, 0.f};
    if (node < n) {
        float s[8], v[8];
        uint4 u = *(const uint4*)(Hs + (size_t)node * 64 + cg);
        unpack8(u, s);
        int b = rowptr[node];
        int deg = rowptr[node + 1] - b;
        int j = 0;
        for (; j + 4 <= deg; j += 4) {
            int i0 = col[b + j], i1 = col[b + j + 1], i2 = col[b + j + 2], i3 = col[b + j + 3];
            uint4 u0 = *(const uint4*)(Hs + (size_t)i0 * 64 + cg);
            uint4 u1 = *(const uint4*)(Hs + (size_t)i1 * 64 + cg);
            uint4 u2 = *(const uint4*)(Hs + (size_t)i2 * 64 + cg);
            uint4 u3 = *(const uint4*)(Hs + (size_t)i3 * 64 + cg);
            unpack8(u0, v);
            #pragma unroll
            for (int q = 0; q < 8; ++q) s[q] += v[q];
            unpack8(u1, v);
            #pragma unroll
            for (int q = 0; q < 8; ++q) s[q] += v[q];
            unpack8(u2, v);
            #pragma unroll
            for (int q = 0; q < 8; ++q) s[q] += v[q];
            unpack8(u3, v);
            #pragma unroll
            for (int q = 0; q < 8; ++q) s[q] += v[q];
        }
        for (; j < deg; ++j) {
            uint4 u0 = *(const uint4*)(Hs + (size_t)col[b + j] * 64 + cg);
            unpack8(u0, v);
            #pragma unroll
            for (int q = 0; q < 8; ++q) s[q] += v[q];
        }
        float dn = dinv[node];
        #pragma unroll
        for (int q = 0; q < 8; ++q) o[q] = s[q] * dn;
        uint4 w;
        w.x = (uint)f2bf(o[0]) | ((uint)f2bf(o[1]) << 16);
        w.y = (uint)f2bf(o[2]) | ((uint)f2bf(o[3]) << 16);
        w.z = (uint)f2bf(o[4]) | ((uint)f2bf(o[5]) << 16);
        w.w = (uint)f2bf(o[6]) | ((uint)f2bf(o[7]) << 16);
        *(uint4*)(outp + (size_t)node * 64 + cg) = w;
    }
    __shared__ float ls[256][8];
    __shared__ float ls2[256][8];
    #pragma unroll
    for (int q = 0; q < 8; ++q) { ls[tid][q] = o[q]; ls2[tid][q] = o[q] * o[q]; }
    __syncthreads();
    for (int off = 128; off >= 8; off >>= 1) {
        if (tid < off) {
            #pragma unroll
            for (int q = 0; q < 8; ++q) {
                ls[tid][q] += ls[tid + off][q];
                ls2[tid][q] += ls2[tid + off][q];
            }
        }
        __syncthreads();
    }
    if (tid < 8) {
        #pragma unroll
        for (int q = 0; q < 8; ++q) {
            part[(size_t)blockIdx.x * 64 + tid * 8 + q] = ls[tid][q];
            part[(size_t)(nblk + blockIdx.x) * 64 + tid * 8 + q] = ls2[tid][q];
        }
    }
}

// ---------------- aggregation with fused BN2+ReLU+dinv transform (conv3, no stats) ----------------
// T(v,j) = relu(v*scale[c]+shift[c]) * dinv[j];  out[i] = dinv[i] * (T(Hs[i],i) + sum T(Hs[src],src))

__global__ __launch_bounds__(256) void k_agg_tr(
    const ushort* __restrict__ Hs, const float* __restrict__ dinv,
    const int* __restrict__ rowptr, const int* __restrict__ col,
    ushort* __restrict__ outp, int n,
    const float* __restrict__ scale, const float* __restrict__ shift)
{
    int gt = blockIdx.x * blockDim.x + threadIdx.x;
    int lane = gt & 63;
    int sub = lane >> 3;
    int cg = (lane & 7) << 3;
    int node = (gt >> 6) * 8 + sub;
    if (node >= n) return;
    float sc[8], sh[8];
    #pragma unroll
    for (int q = 0; q < 8; ++q) { sc[q] = scale[cg + q]; sh[q] = shift[cg + q]; }
    float s[8], v[8];
    {
        uint4 u = *(const uint4*)(Hs + (size_t)node * 64 + cg);
        unpack8(u, v);
        float dv = dinv[node];
        #pragma unroll
        for (int q = 0; q < 8; ++q) s[q] = fmaxf(v[q] * sc[q] + sh[q], 0.f) * dv;
    }
    int b = rowptr[node];
    int deg = rowptr[node + 1] - b;
    int j = 0;
    for (; j + 4 <= deg; j += 4) {
        int i0 = col[b + j], i1 = col[b + j + 1], i2 = col[b + j + 2], i3 = col[b + j + 3];
        float d0 = dinv[i0], d1 = dinv[i1], d2 = dinv[i2], d3 = dinv[i3];
        uint4 u0 = *(const uint4*)(Hs + (size_t)i0 * 64 + cg);
        uint4 u1 = *(const uint4*)(Hs + (size_t)i1 * 64 + cg);
        uint4 u2 = *(const uint4*)(Hs + (size_t)i2 * 64 + cg);
        uint4 u3 = *(const uint4*)(Hs + (size_t)i3 * 64 + cg);
        unpack8(u0, v);
        #pragma unroll
        for (int q = 0; q < 8; ++q) s[q] += fmaxf(v[q] * sc[q] + sh[q], 0.f) * d0;
        unpack8(u1, v);
        #pragma unroll
        for (int q = 0; q < 8; ++q) s[q] += fmaxf(v[q] * sc[q] + sh[q], 0.f) * d1;
        unpack8(u2, v);
        #pragma unroll
        for (int q = 0; q < 8; ++q) s[q] += fmaxf(v[q] * sc[q] + sh[q], 0.f) * d2;
        unpack8(u3, v);
        #pragma unroll
        for (int q = 0; q < 8; ++q) s[q] += fmaxf(v[q] * sc[q] + sh[q], 0.f) * d3;
    }
    for (; j < deg; ++j) {
        int i0 = col[b + j];
        float d0 = dinv[i0];
        uint4 u0 = *(const uint4*)(Hs + (size_t)i0 * 64 + cg);
        unpack8(u0, v);
        #pragma unroll
        for (int q = 0; q < 8; ++q) s[q] += fmaxf(v[q] * sc[q] + sh[q], 0.f) * d0;
    }
    float dn = dinv[node];
    uint4 w;
    w.x = (uint)f2bf(s[0] * dn) | ((uint)f2bf(s[1] * dn) << 16);
    w.y = (uint)f2bf(s[2] * dn) | ((uint)f2bf(s[3] * dn) << 16);
    w.z = (uint)f2bf(s[4] * dn) | ((uint)f2bf(s[5] * dn) << 16);
    w.w = (uint)f2bf(s[6] * dn) | ((uint)f2bf(s[7] * dn) << 16);
    *(uint4*)(outp + (size_t)node * 64 + cg) = w;
}

// ---------------- BN statistics (bf16 input, used for W=256 on bufCb) ----------------

__global__ __launch_bounds__(256) void k_bnstat1_bf(const ushort* __restrict__ X,
                                                    float* __restrict__ part, int n, int W) {
    int cols8 = W >> 3;
    int c8 = threadIdx.x & (cols8 - 1);
    int rsub = threadIdx.x / cols8;
    int lanes = 256 / cols8;
    int nrg = (n + lanes - 1) / lanes;
    float s[8] = {0.f}, s2[8] = {0.f};
    for (int rg = blockIdx.x; rg < nrg; rg += gridDim.x) {
        int r = rg * lanes + rsub;
        if (r < n) {
            uint4 u = *(const uint4*)(X + (size_t)r * W + (c8 << 3));
            float v[8];
            unpack8(u, v);
            #pragma unroll
            for (int j = 0; j < 8; ++j) { s[j] += v[j]; s2[j] += v[j] * v[j]; }
        }
    }
    __shared__ float ls[256][8];
    __shared__ float ls2[256][8];
    #pragma unroll
    for (int j = 0; j < 8; ++j) { ls[threadIdx.x][j] = s[j]; ls2[threadIdx.x][j] = s2[j]; }
    __syncthreads();
    for (int off = lanes >> 1; off > 0; off >>= 1) {
        if (rsub < off) {
            int i = threadIdx.x, jdx = threadIdx.x + off * cols8;
            #pragma unroll
            for (int j = 0; j < 8; ++j) { ls[i][j] += ls[jdx][j]; ls2[i][j] += ls2[jdx][j]; }
        }
        __syncthreads();
    }
    if (rsub == 0) {
        #pragma unroll
        for (int j = 0; j < 8; ++j) {
            part[(size_t)blockIdx.x * W + (c8 << 3) + j] = ls[c8][j];
            part[(size_t)(gridDim.x + blockIdx.x) * W + (c8 << 3) + j] = ls2[c8][j];
        }
    }
}

__global__ __launch_bounds__(1024) void k_bnstat2(const float* __restrict__ part,
                                                  const float* __restrict__ g,
                                                  const float* __restrict__ be,
                                                  float* __restrict__ scale,
                                                  float* __restrict__ shift,
                                                  int nblk, int W, float inv_n) {
    int t = threadIdx.x;
    int c = t & (W - 1);
    int q = t / W;
    int nq = 1024 / W;
    int per = (nblk + nq - 1) / nq;
    int b0 = q * per, b1 = min(b0 + per, nblk);
    float s = 0.f, s2 = 0.f;
    for (int b = b0; b < b1; ++b) {
        s  += part[(size_t)b * W + c];
        s2 += part[(size_t)(nblk + b) * W + c];
    }
    __shared__ float ls[1024], ls2[1024];
    ls[t] = s;
    ls2[t] = s2;
    __syncthreads();
    if (q == 0) {
        for (int k = 1; k < nq; ++k) {
            s += ls[k * W + c];
            s2 += ls2[k * W + c];
        }
        float m = s * inv_n;
        float v = s2 * inv_n - m * m;
        float sc = g[c] * rsqrtf(v + BN_EPS);
        scale[c] = sc;
        shift[c] = be[c] - m * sc;
    }
}

// ---------------- final: out = relu(h*scale[c] + shift[c] + x), h bf16, W=256 ----------------

__global__ void k_final_bf(const ushort* __restrict__ h, const float* __restrict__ x,
                           float* __restrict__ out,
                           const float* __restrict__ scale, const float* __restrict__ shift, int n) {
    int idx = blockIdx.x * blockDim.x + threadIdx.x;
    int total = n * 32;
    for (int i = idx; i < total; i += gridDim.x * blockDim.x) {
        int row = i >> 5;
        int c8 = (i & 31) << 3;
        uint4 u = *(const uint4*)(h + (size_t)row * 256 + c8);
        float v[8];
        unpack8(u, v);
        const float* xp = x + (size_t)row * 256 + c8;
        float4 x0 = *(const float4*)xp;
        float4 x1 = *(const float4*)(xp + 4);
        float xv[8] = {x0.x, x0.y, x0.z, x0.w, x1.x, x1.y, x1.z, x1.w};
        float o[8];
        #pragma unroll
        for (int j = 0; j < 8; ++j)
            o[j] = fmaxf(v[j] * scale[c8 + j] + shift[c8 + j] + xv[j], 0.f);
        float* op = out + (size_t)row * 256 + c8;
        *(float4*)op = make_float4(o[0], o[1], o[2], o[3]);
        *(float4*)(op + 4) = make_float4(o[4], o[5], o[6], o[7]);
    }
}

// ---------------- launch ----------------

extern "C" void kernel_launch(void* const* d_in, const int* in_sizes, int n_in,
                              void* d_out, int out_size, void* d_ws, size_t ws_size,
                              hipStream_t stream) {
    const float* x   = (const float*)d_in[0];
    const int*   ei  = (const int*)d_in[1];
    const int    N   = in_sizes[2];
    const int    E   = in_sizes[1] / 2;
    const float* W1  = (const float*)d_in[3];
    const float* g1  = (const float*)d_in[5];
    const float* be1 = (const float*)d_in[6];
    const float* W2  = (const float*)d_in[7];
    const float* g2  = (const float*)d_in[9];
    const float* be2 = (const float*)d_in[10];
    const float* W3  = (const float*)d_in[11];
    const float* g3  = (const float*)d_in[13];
    const float* be3 = (const float*)d_in[14];
    float* out = (float*)d_out;

    char* p = (char*)d_ws;
    auto alloc = [&](size_t bytes) {
        char* q = p;
        p += (bytes + 255) & ~(size_t)255;
        return q;
    };
    const int NCB = (N + CB_NODES - 1) >> CB_SHIFT;
    const int aggb = (((N + 7) / 8) * 64 + 255) / 256;   // 32 nodes per block
    size_t part_elems = (size_t)2 * aggb * 64;
    size_t part_elems3 = (size_t)2 * NBLK_STAT * 256;
    if (part_elems3 > part_elems) part_elems = part_elems3;

    int*    cbcnt  = (int*)alloc((size_t)NCB * 4);
    int*    bbase  = (int*)alloc((size_t)(NCB + 1) * 4);
    int*    claim  = (int*)alloc((size_t)NCB * 4);
    int*    rowptr = (int*)alloc((size_t)(N + 1) * 4);
    float*  dinv   = (float*)alloc((size_t)N * 4);
    uint*   keys   = (uint*)alloc((size_t)E * 4);
    int*    colv   = (int*)alloc((size_t)E * 4);
    ushort* bufAb  = (ushort*)alloc((size_t)N * 64 * 2);
    ushort* bufBb  = (ushort*)alloc((size_t)N * 64 * 2);
    ushort* bufCb  = (ushort*)alloc((size_t)N * 256 * 2);
    float*  part   = (float*)alloc(part_elems * 4);
    float*  scale  = (float*)alloc(256 * 4);
    float*  shift  = (float*)alloc(256 * 4);

    const int* srcp = ei;
    const int* dstp = ei + E;

    hipMemsetAsync(cbcnt, 0, (size_t)NCB * 4, stream);
    k_degcb<<<1024, 256, 0, stream>>>(dstp, cbcnt, E, NCB);
    k_scancb<<<1, 512, 0, stream>>>(cbcnt, bbase, claim, rowptr, NCB, N, E);
    int p1b = (E + P1_CHUNK - 1) / P1_CHUNK;
    k_p1<<<p1b, 256, 0, stream>>>(srcp, dstp, claim, keys, E, NCB);
    k_build<<<NCB, 256, 0, stream>>>(keys, bbase, rowptr, dinv, colv, N);

    dim3 gemm_g((N + 63) / 64, 1);
    dim3 gemm3_g((N + 63) / 64, 4);

    // conv1: A1 = (x @ W1) * dinv (bf16) -> agg+stats -> G1 (pre-BN)
    k_gemm_mfma<<<gemm_g, 256, 0, stream>>>(x, nullptr, W1, bufAb, nullptr,
                                            nullptr, nullptr, dinv, N, 256, 64);
    k_agg_st<<<aggb, 256, 0, stream>>>(bufAb, dinv, rowptr, colv, bufBb, part, N, aggb);
    k_bnstat2<<<1, 1024, 0, stream>>>(part, g1, be1, scale, shift, aggb, 64, 1.0f / N);

    // conv2: BN1+ReLU fused into GEMM A-stage; ×dinv epilogue -> agg+stats -> G2 (pre-BN)
    k_gemm_mfma<<<gemm_g, 256, 0, stream>>>(nullptr, bufBb, W2, bufAb, nullptr,
                                            scale, shift, dinv, N, 64, 64);
    k_agg_st<<<aggb, 256, 0, stream>>>(bufAb, dinv, rowptr, colv, bufBb, part, N, aggb);
    k_bnstat2<<<1, 1024, 0, stream>>>(part, g2, be2, scale, shift, aggb, 64, 1.0f / N);

    // conv3 (agg-first): transform-agg -> GEMM3 -> bufCb (bf16) -> BN3 stats -> final
    k_agg_tr<<<aggb, 256, 0, stream>>>(bufBb, dinv, rowptr, colv, bufAb, N, scale, shift);
    k_gemm_mfma<<<gemm3_g, 256, 0, stream>>>(nullptr, bufAb, W3, bufCb, nullptr,
                                             nullptr, nullptr, nullptr, N, 64, 256);
    k_bnstat1_bf<<<NBLK_STAT, 256, 0, stream>>>(bufCb, part, N, 256);
    k_bnstat2<<<1, 1024, 0, stream>>>(part, g3, be3, scale, shift, NBLK_STAT, 256, 1.0f / N);

    k_final_bf<<<2048, 256, 0, stream>>>(bufCb, x, out, scale, shift, N);
}

// Round 9
// 281.429 us; speedup vs baseline: 1.0452x; 1.0452x over previous
//
#include <hip/hip_runtime.h>
#include <hip/hip_bf16.h>

#define BN_EPS 1e-5f
#define CB_SHIFT 9            // 512 nodes per coarse bucket
#define CB_NODES 512
#define CAP 32768             // padded per-bucket capacity (E/ncb ~ 8k; 4x headroom)
#define P1_CHUNK 2048
#define AGB 512               // agg blocks (grid-stride)

typedef __attribute__((ext_vector_type(8))) short short8;
typedef __attribute__((ext_vector_type(4))) float f32x4;

__device__ __forceinline__ ushort f2bf(float x) {
    uint u = __float_as_uint(x);
    u += 0x7FFF + ((u >> 16) & 1);      // round-to-nearest-even
    return (ushort)(u >> 16);
}
__device__ __forceinline__ float bf2f(uint h) { return __uint_as_float(h << 16); }

__device__ __forceinline__ void unpack8(uint4 u, float* v) {
    v[0] = bf2f(u.x & 0xffffu); v[1] = bf2f(u.x >> 16);
    v[2] = bf2f(u.y & 0xffffu); v[3] = bf2f(u.y >> 16);
    v[4] = bf2f(u.z & 0xffffu); v[5] = bf2f(u.z >> 16);
    v[6] = bf2f(u.w & 0xffffu); v[7] = bf2f(u.w >> 16);
}

// ---------------- weight pre-transpose: WT[out][K] bf16 ----------------

__global__ __launch_bounds__(256) void k_prepw(const float* __restrict__ W1,
                                               const float* __restrict__ W2,
                                               const float* __restrict__ W3,
                                               ushort* __restrict__ WT1,
                                               ushort* __restrict__ WT2,
                                               ushort* __restrict__ WT3) {
    int b = blockIdx.x;
    const float* src; ushort* dst; int K, OUT, out;
    if (b < 64)       { out = b;       K = 256; OUT = 64;  src = W1; dst = WT1; }
    else if (b < 128) { out = b - 64;  K = 64;  OUT = 64;  src = W2; dst = WT2; }
    else              { out = b - 128; K = 64;  OUT = 256; src = W3; dst = WT3; }
    for (int k = threadIdx.x; k < K; k += 256)
        dst[(size_t)out * K + k] = f2bf(src[(size_t)k * OUT + out]);
}

// ---------------- CSR build: fixed-capacity buckets ----------------
// pass 1: scatter edges into bucket-padded key array. key = (dst_local<<17)|src (N<=131072)

__global__ __launch_bounds__(256) void k_p1(const int* __restrict__ src,
                                            const int* __restrict__ dst,
                                            int* __restrict__ claim,
                                            uint* __restrict__ keys, int E) {
    __shared__ int hist[128];
    __shared__ int wpos[128];
    int tid = threadIdx.x;
    int c0 = blockIdx.x * P1_CHUNK;
    if (tid < 128) hist[tid] = 0;
    __syncthreads();
    for (int i = tid; i < P1_CHUNK; i += 256) {
        int e = c0 + i;
        if (e < E) atomicAdd(&hist[dst[e] >> CB_SHIFT], 1);
    }
    __syncthreads();
    if (tid < 128) wpos[tid] = hist[tid] ? atomicAdd(&claim[tid], hist[tid]) : 0;
    __syncthreads();
    for (int i = tid; i < P1_CHUNK; i += 256) {
        int e = c0 + i;
        if (e < E) {
            int d = dst[e];
            int b = d >> CB_SHIFT;
            uint key = ((uint)(d & (CB_NODES - 1)) << 17) | (uint)src[e];
            int slot = atomicAdd(&wpos[b], 1);
            keys[(size_t)b * CAP + slot] = key;
        }
    }
}

// pass 2 per bucket: LDS hist -> local scan -> row{beg,deg}/dinv -> scatter col (padded space)

__global__ __launch_bounds__(256) void k_build(const uint* __restrict__ keys,
                                               const int* __restrict__ claim,
                                               int2* __restrict__ row,
                                               float* __restrict__ dinv,
                                               int* __restrict__ col, int n) {
    __shared__ int hist[CB_NODES];
    __shared__ int excl[CB_NODES];
    __shared__ int lpos[CB_NODES];
    __shared__ int ps[256];
    int t = threadIdx.x;
    int cb = blockIdx.x;
    int cnt = claim[cb];
    const uint* kb = keys + (size_t)cb * CAP;
    int base = cb * CAP;
    for (int i = t; i < CB_NODES; i += 256) { hist[i] = 0; lpos[i] = 0; }
    __syncthreads();
    for (int j = t; j < cnt; j += 256) atomicAdd(&hist[kb[j] >> 17], 1);
    __syncthreads();
    ps[t] = hist[2 * t] + hist[2 * t + 1];
    __syncthreads();
    for (int off = 1; off < 256; off <<= 1) {
        int v = ps[t];
        int a = (t >= off) ? ps[t - off] : 0;
        __syncthreads();
        ps[t] = v + a;
        __syncthreads();
    }
    int b0 = (t == 0) ? 0 : ps[t - 1];
    excl[2 * t] = b0;
    excl[2 * t + 1] = b0 + hist[2 * t];
    __syncthreads();
    for (int i = t; i < CB_NODES; i += 256) {
        int node = (cb << CB_SHIFT) + i;
        if (node < n) {
            row[node] = make_int2(base + excl[i], hist[i]);
            dinv[node] = rsqrtf((float)hist[i] + 1.0f);
        }
    }
    __syncthreads();
    for (int j = t; j < cnt; j += 256) {
        uint key = kb[j];
        int nl = key >> 17;
        col[base + excl[nl] + atomicAdd(&lpos[nl], 1)] = (int)(key & 0x1FFFFu);
    }
}

// ---------------- MFMA bf16 GEMM: C[n,OUT] = transform(A[n,K]) @ W ----------------
// WT is pre-transposed bf16 [OUT][K]. transform (scale!=null): a=relu(a*sc+sh).
// epilogue ×dinv[row] if dinv; optional fused BN partial stats (part!=null):
// part[bx*OUTW + col] = per-block row-sum, part[(nblk+bx)*OUTW + col] = sumsq.

__global__ __launch_bounds__(256) void k_gemm_mfma(
    const float* __restrict__ Af, const ushort* __restrict__ Ab,
    const ushort* __restrict__ WT,
    ushort* __restrict__ Cb, float* __restrict__ Cf,
    const float* __restrict__ scale, const float* __restrict__ shift,
    const float* __restrict__ dinv,
    float* __restrict__ part, int nblk, int OUTW,
    int n, int K, int OUT)
{
    __shared__ ushort As[64][40];   // [row][k]
    __shared__ ushort Wt[64][40];   // [col][k]
    __shared__ float ssum[64][17];
    __shared__ float ssq[64][17];
    const int row0 = blockIdx.x * 64;
    const int col0 = blockIdx.y * 64;
    const int tid = threadIdx.x;
    const int wv = tid >> 6;
    const int lane = tid & 63;
    const int fr = lane & 15;
    const int kb = lane >> 4;

    const int ar  = tid >> 2;         // A stage: row 0..63
    const int akc = (tid & 3) << 3;   // A stage: k offset 0,8,16,24
    const int wc  = tid >> 2;         // W stage: col 0..63
    const int wkc = (tid & 3) << 3;   // W stage: k offset

    f32x4 acc[4];
    acc[0] = acc[1] = acc[2] = acc[3] = (f32x4){0.f, 0.f, 0.f, 0.f};

    for (int k0 = 0; k0 < K; k0 += 32) {
        int gr = row0 + ar;
        if (Af) {
            float v[8];
            if (gr < n) {
                const float* ap = Af + (size_t)gr * K + k0 + akc;
                float4 x0 = *(const float4*)ap;
                float4 x1 = *(const float4*)(ap + 4);
                v[0] = x0.x; v[1] = x0.y; v[2] = x0.z; v[3] = x0.w;
                v[4] = x1.x; v[5] = x1.y; v[6] = x1.z; v[7] = x1.w;
            } else {
                #pragma unroll
                for (int j = 0; j < 8; ++j) v[j] = 0.f;
            }
            uint4 w;
            w.x = (uint)f2bf(v[0]) | ((uint)f2bf(v[1]) << 16);
            w.y = (uint)f2bf(v[2]) | ((uint)f2bf(v[3]) << 16);
            w.z = (uint)f2bf(v[4]) | ((uint)f2bf(v[5]) << 16);
            w.w = (uint)f2bf(v[6]) | ((uint)f2bf(v[7]) << 16);
            *(uint4*)&As[ar][akc] = w;
        } else if (scale) {
            float v[8];
            if (gr < n) {
                uint4 u = *(const uint4*)(Ab + (size_t)gr * K + k0 + akc);
                unpack8(u, v);
                #pragma unroll
                for (int j = 0; j < 8; ++j)
                    v[j] = fmaxf(v[j] * scale[k0 + akc + j] + shift[k0 + akc + j], 0.f);
            } else {
                #pragma unroll
                for (int j = 0; j < 8; ++j) v[j] = 0.f;
            }
            uint4 w;
            w.x = (uint)f2bf(v[0]) | ((uint)f2bf(v[1]) << 16);
            w.y = (uint)f2bf(v[2]) | ((uint)f2bf(v[3]) << 16);
            w.z = (uint)f2bf(v[4]) | ((uint)f2bf(v[5]) << 16);
            w.w = (uint)f2bf(v[6]) | ((uint)f2bf(v[7]) << 16);
            *(uint4*)&As[ar][akc] = w;
        } else {
            uint4 u = make_uint4(0, 0, 0, 0);
            if (gr < n) u = *(const uint4*)(Ab + (size_t)gr * K + k0 + akc);
            *(uint4*)&As[ar][akc] = u;
        }
        // W stage: vector copy from pre-transposed WT
        {
            uint4 u = *(const uint4*)(WT + (size_t)(col0 + wc) * K + k0 + wkc);
            *(uint4*)&Wt[wc][wkc] = u;
        }
        __syncthreads();
        short8 a = *(const short8*)&As[16 * wv + fr][kb << 3];
        #pragma unroll
        for (int ct = 0; ct < 4; ++ct) {
            short8 b = *(const short8*)&Wt[ct * 16 + fr][kb << 3];
            acc[ct] = __builtin_amdgcn_mfma_f32_16x16x32_bf16(a, b, acc[ct], 0, 0, 0);
        }
        __syncthreads();
    }

    // epilogue: D row = 16*wv + kb*4 + r, col = ct*16 + fr
    const int contrib = wv * 4 + kb;   // 0..15
    #pragma unroll
    for (int ct = 0; ct < 4; ++ct) {
        float psum = 0.f, psq = 0.f;
        #pragma unroll
        for (int r = 0; r < 4; ++r) {
            int gr = row0 + 16 * wv + (kb << 2) + r;
            if (gr >= n) continue;
            float dv = dinv ? dinv[gr] : 1.0f;
            float val = acc[ct][r] * dv;
            int gc = col0 + ct * 16 + fr;
            if (Cb) Cb[(size_t)gr * OUT + gc] = f2bf(val);
            else    Cf[(size_t)gr * OUT + gc] = val;
            psum += val;
            psq += val * val;
        }
        if (part) {
            ssum[ct * 16 + fr][contrib] = psum;
            ssq[ct * 16 + fr][contrib] = psq;
        }
    }
    if (part) {
        __syncthreads();
        if (tid < 64) {
            float s = 0.f, s2 = 0.f;
            #pragma unroll
            for (int i = 0; i < 16; ++i) { s += ssum[tid][i]; s2 += ssq[tid][i]; }
            part[(size_t)blockIdx.x * OUTW + col0 + tid] = s;
            part[(size_t)(nblk + blockIdx.x) * OUTW + col0 + tid] = s2;
        }
    }
}

// ---------------- aggregation + fused BN partial stats (conv1/conv2) ----------------
// out[i] = dinv[i] * (Hs[i] + sum_{src} Hs[src]); grid-stride, 32 nodes/block-iter.

__global__ __launch_bounds__(256) void k_agg_st(
    const ushort* __restrict__ Hs, const float* __restrict__ dinv,
    const int2* __restrict__ row, const int* __restrict__ col,
    ushort* __restrict__ outp, float* __restrict__ part, int n, int nblk)
{
    int tid = threadIdx.x;
    int sub = (tid & 63) >> 3;
    int wvb = tid >> 6;                 // wave in block 0..3
    int cg = (tid & 7) << 3;
    int nch = (n + 31) >> 5;
    float asum[8] = {0.f}, asq[8] = {0.f};
    for (int ch = blockIdx.x; ch < nch; ch += gridDim.x) {
        int node = (ch << 5) + (wvb << 3) + sub;
        if (node >= n) continue;
        float s[8], v[8];
        uint4 u = *(const uint4*)(Hs + (size_t)node * 64 + cg);
        unpack8(u, s);
        int2 rd = row[node];
        int b = rd.x, deg = rd.y;
        int j = 0;
        for (; j + 4 <= deg; j += 4) {
            int i0 = col[b + j], i1 = col[b + j + 1], i2 = col[b + j + 2], i3 = col[b + j + 3];
            uint4 u0 = *(const uint4*)(Hs + (size_t)i0 * 64 + cg);
            uint4 u1 = *(const uint4*)(Hs + (size_t)i1 * 64 + cg);
            uint4 u2 = *(const uint4*)(Hs + (size_t)i2 * 64 + cg);
            uint4 u3 = *(const uint4*)(Hs + (size_t)i3 * 64 + cg);
            unpack8(u0, v);
            #pragma unroll
            for (int q = 0; q < 8; ++q) s[q] += v[q];
            unpack8(u1, v);
            #pragma unroll
            for (int q = 0; q < 8; ++q) s[q] += v[q];
            unpack8(u2, v);
            #pragma unroll
            for (int q = 0; q < 8; ++q) s[q] += v[q];
            unpack8(u3, v);
            #pragma unroll
            for (int q = 0; q < 8; ++q) s[q] += v[q];
        }
        for (; j < deg; ++j) {
            uint4 u0 = *(const uint4*)(Hs + (size_t)col[b + j] * 64 + cg);
            unpack8(u0, v);
            #pragma unroll
            for (int q = 0; q < 8; ++q) s[q] += v[q];
        }
        float dn = dinv[node];
        uint4 w;
        float o[8];
        #pragma unroll
        for (int q = 0; q < 8; ++q) {
            o[q] = s[q] * dn;
            asum[q] += o[q];
            asq[q] += o[q] * o[q];
        }
        w.x = (uint)f2bf(o[0]) | ((uint)f2bf(o[1]) << 16);
        w.y = (uint)f2bf(o[2]) | ((uint)f2bf(o[3]) << 16);
        w.z = (uint)f2bf(o[4]) | ((uint)f2bf(o[5]) << 16);
        w.w = (uint)f2bf(o[6]) | ((uint)f2bf(o[7]) << 16);
        *(uint4*)(outp + (size_t)node * 64 + cg) = w;
    }
    __shared__ float ls[256][8];
    __shared__ float ls2[256][8];
    #pragma unroll
    for (int q = 0; q < 8; ++q) { ls[tid][q] = asum[q]; ls2[tid][q] = asq[q]; }
    __syncthreads();
    for (int off = 128; off >= 8; off >>= 1) {
        if (tid < off) {
            #pragma unroll
            for (int q = 0; q < 8; ++q) {
                ls[tid][q] += ls[tid + off][q];
                ls2[tid][q] += ls2[tid + off][q];
            }
        }
        __syncthreads();
    }
    if (tid < 8) {
        #pragma unroll
        for (int q = 0; q < 8; ++q) {
            part[(size_t)blockIdx.x * 64 + tid * 8 + q] = ls[tid][q];
            part[(size_t)(nblk + blockIdx.x) * 64 + tid * 8 + q] = ls2[tid][q];
        }
    }
}

// ---------------- aggregation with fused BN2+ReLU+dinv transform (conv3) ----------------

__global__ __launch_bounds__(256) void k_agg_tr(
    const ushort* __restrict__ Hs, const float* __restrict__ dinv,
    const int2* __restrict__ row, const int* __restrict__ col,
    ushort* __restrict__ outp, int n,
    const float* __restrict__ scale, const float* __restrict__ shift)
{
    int tid = threadIdx.x;
    int sub = (tid & 63) >> 3;
    int wvb = tid >> 6;
    int cg = (tid & 7) << 3;
    float sc[8], sh[8];
    #pragma unroll
    for (int q = 0; q < 8; ++q) { sc[q] = scale[cg + q]; sh[q] = shift[cg + q]; }
    int nch = (n + 31) >> 5;
    for (int ch = blockIdx.x; ch < nch; ch += gridDim.x) {
        int node = (ch << 5) + (wvb << 3) + sub;
        if (node >= n) continue;
        float s[8], v[8];
        {
            uint4 u = *(const uint4*)(Hs + (size_t)node * 64 + cg);
            unpack8(u, v);
            float dv = dinv[node];
            #pragma unroll
            for (int q = 0; q < 8; ++q) s[q] = fmaxf(v[q] * sc[q] + sh[q], 0.f) * dv;
        }
        int2 rd = row[node];
        int b = rd.x, deg = rd.y;
        int j = 0;
        for (; j + 4 <= deg; j += 4) {
            int i0 = col[b + j], i1 = col[b + j + 1], i2 = col[b + j + 2], i3 = col[b + j + 3];
            float d0 = dinv[i0], d1 = dinv[i1], d2 = dinv[i2], d3 = dinv[i3];
            uint4 u0 = *(const uint4*)(Hs + (size_t)i0 * 64 + cg);
            uint4 u1 = *(const uint4*)(Hs + (size_t)i1 * 64 + cg);
            uint4 u2 = *(const uint4*)(Hs + (size_t)i2 * 64 + cg);
            uint4 u3 = *(const uint4*)(Hs + (size_t)i3 * 64 + cg);
            unpack8(u0, v);
            #pragma unroll
            for (int q = 0; q < 8; ++q) s[q] += fmaxf(v[q] * sc[q] + sh[q], 0.f) * d0;
            unpack8(u1, v);
            #pragma unroll
            for (int q = 0; q < 8; ++q) s[q] += fmaxf(v[q] * sc[q] + sh[q], 0.f) * d1;
            unpack8(u2, v);
            #pragma unroll
            for (int q = 0; q < 8; ++q) s[q] += fmaxf(v[q] * sc[q] + sh[q], 0.f) * d2;
            unpack8(u3, v);
            #pragma unroll
            for (int q = 0; q < 8; ++q) s[q] += fmaxf(v[q] * sc[q] + sh[q], 0.f) * d3;
        }
        for (; j < deg; ++j) {
            int i0 = col[b + j];
            float d0 = dinv[i0];
            uint4 u0 = *(const uint4*)(Hs + (size_t)i0 * 64 + cg);
            unpack8(u0, v);
            #pragma unroll
            for (int q = 0; q < 8; ++q) s[q] += fmaxf(v[q] * sc[q] + sh[q], 0.f) * d0;
        }
        float dn = dinv[node];
        uint4 w;
        w.x = (uint)f2bf(s[0] * dn) | ((uint)f2bf(s[1] * dn) << 16);
        w.y = (uint)f2bf(s[2] * dn) | ((uint)f2bf(s[3] * dn) << 16);
        w.z = (uint)f2bf(s[4] * dn) | ((uint)f2bf(s[5] * dn) << 16);
        w.w = (uint)f2bf(s[6] * dn) | ((uint)f2bf(s[7] * dn) << 16);
        *(uint4*)(outp + (size_t)node * 64 + cg) = w;
    }
}

// ---------------- BN stat finalize ----------------

__global__ __launch_bounds__(1024) void k_bnstat2(const float* __restrict__ part,
                                                  const float* __restrict__ g,
                                                  const float* __restrict__ be,
                                                  float* __restrict__ scale,
                                                  float* __restrict__ shift,
                                                  int nblk, int W, float inv_n) {
    int t = threadIdx.x;
    int c = t & (W - 1);
    int q = t / W;
    int nq = 1024 / W;
    int per = (nblk + nq - 1) / nq;
    int b0 = q * per, b1 = min(b0 + per, nblk);
    float s = 0.f, s2 = 0.f;
    for (int b = b0; b < b1; ++b) {
        s  += part[(size_t)b * W + c];
        s2 += part[(size_t)(nblk + b) * W + c];
    }
    __shared__ float ls[1024], ls2[1024];
    ls[t] = s;
    ls2[t] = s2;
    __syncthreads();
    if (q == 0) {
        for (int k = 1; k < nq; ++k) {
            s += ls[k * W + c];
            s2 += ls2[k * W + c];
        }
        float m = s * inv_n;
        float v = s2 * inv_n - m * m;
        float sc = g[c] * rsqrtf(v + BN_EPS);
        scale[c] = sc;
        shift[c] = be[c] - m * sc;
    }
}

// ---------------- final: out = relu(h*scale[c] + shift[c] + x), h bf16, W=256 ----------------

__global__ void k_final_bf(const ushort* __restrict__ h, const float* __restrict__ x,
                           float* __restrict__ out,
                           const float* __restrict__ scale, const float* __restrict__ shift, int n) {
    int idx = blockIdx.x * blockDim.x + threadIdx.x;
    int total = n * 32;
    for (int i = idx; i < total; i += gridDim.x * blockDim.x) {
        int row = i >> 5;
        int c8 = (i & 31) << 3;
        uint4 u = *(const uint4*)(h + (size_t)row * 256 + c8);
        float v[8];
        unpack8(u, v);
        const float* xp = x + (size_t)row * 256 + c8;
        float4 x0 = *(const float4*)xp;
        float4 x1 = *(const float4*)(xp + 4);
        float xv[8] = {x0.x, x0.y, x0.z, x0.w, x1.x, x1.y, x1.z, x1.w};
        float o[8];
        #pragma unroll
        for (int j = 0; j < 8; ++j)
            o[j] = fmaxf(v[j] * scale[c8 + j] + shift[c8 + j] + xv[j], 0.f);
        float* op = out + (size_t)row * 256 + c8;
        *(float4*)op = make_float4(o[0], o[1], o[2], o[3]);
        *(float4*)(op + 4) = make_float4(o[4], o[5], o[6], o[7]);
    }
}

// ---------------- launch ----------------

extern "C" void kernel_launch(void* const* d_in, const int* in_sizes, int n_in,
                              void* d_out, int out_size, void* d_ws, size_t ws_size,
                              hipStream_t stream) {
    const float* x   = (const float*)d_in[0];
    const int*   ei  = (const int*)d_in[1];
    const int    N   = in_sizes[2];
    const int    E   = in_sizes[1] / 2;
    const float* W1  = (const float*)d_in[3];
    const float* g1  = (const float*)d_in[5];
    const float* be1 = (const float*)d_in[6];
    const float* W2  = (const float*)d_in[7];
    const float* g2  = (const float*)d_in[9];
    const float* be2 = (const float*)d_in[10];
    const float* W3  = (const float*)d_in[11];
    const float* g3  = (const float*)d_in[13];
    const float* be3 = (const float*)d_in[14];
    float* out = (float*)d_out;

    char* p = (char*)d_ws;
    auto alloc = [&](size_t bytes) {
        char* q = p;
        p += (bytes + 255) & ~(size_t)255;
        return q;
    };
    const int NCB = (N + CB_NODES - 1) >> CB_SHIFT;
    const int RT1 = (N + 63) / 64;       // gemm row tiles
    size_t part_elems = (size_t)2 * AGB * 64;
    size_t part_elems3 = (size_t)2 * RT1 * 256;
    if (part_elems3 > part_elems) part_elems = part_elems3;

    int*    claim  = (int*)alloc((size_t)NCB * 4);
    int2*   rowv   = (int2*)alloc((size_t)N * 8);
    float*  dinv   = (float*)alloc((size_t)N * 4);
    uint*   keys   = (uint*)alloc((size_t)NCB * CAP * 4);
    int*    colv   = (int*)alloc((size_t)NCB * CAP * 4);
    ushort* WT1    = (ushort*)alloc((size_t)64 * 256 * 2);
    ushort* WT2    = (ushort*)alloc((size_t)64 * 64 * 2);
    ushort* WT3    = (ushort*)alloc((size_t)256 * 64 * 2);
    ushort* bufAb  = (ushort*)alloc((size_t)N * 64 * 2);
    ushort* bufBb  = (ushort*)alloc((size_t)N * 64 * 2);
    ushort* bufCb  = (ushort*)alloc((size_t)N * 256 * 2);
    float*  part   = (float*)alloc(part_elems * 4);
    float*  scale  = (float*)alloc(256 * 4);
    float*  shift  = (float*)alloc(256 * 4);

    const int* srcp = ei;
    const int* dstp = ei + E;

    k_prepw<<<384, 256, 0, stream>>>(W1, W2, W3, WT1, WT2, WT3);
    hipMemsetAsync(claim, 0, (size_t)NCB * 4, stream);
    int p1b = (E + P1_CHUNK - 1) / P1_CHUNK;
    k_p1<<<p1b, 256, 0, stream>>>(srcp, dstp, claim, keys, E);
    k_build<<<NCB, 256, 0, stream>>>(keys, claim, rowv, dinv, colv, N);

    dim3 gemm_g(RT1, 1);
    dim3 gemm3_g(RT1, 4);

    // conv1: A1 = (x @ W1) * dinv (bf16) -> agg+stats -> G1 (pre-BN)
    k_gemm_mfma<<<gemm_g, 256, 0, stream>>>(x, nullptr, WT1, bufAb, nullptr,
                                            nullptr, nullptr, dinv,
                                            nullptr, 0, 0, N, 256, 64);
    k_agg_st<<<AGB, 256, 0, stream>>>(bufAb, dinv, rowv, colv, bufBb, part, N, AGB);
    k_bnstat2<<<1, 1024, 0, stream>>>(part, g1, be1, scale, shift, AGB, 64, 1.0f / N);

    // conv2: BN1+ReLU fused into GEMM A-stage; ×dinv epilogue -> agg+stats -> G2 (pre-BN)
    k_gemm_mfma<<<gemm_g, 256, 0, stream>>>(nullptr, bufBb, WT2, bufAb, nullptr,
                                            scale, shift, dinv,
                                            nullptr, 0, 0, N, 64, 64);
    k_agg_st<<<AGB, 256, 0, stream>>>(bufAb, dinv, rowv, colv, bufBb, part, N, AGB);
    k_bnstat2<<<1, 1024, 0, stream>>>(part, g2, be2, scale, shift, AGB, 64, 1.0f / N);

    // conv3 (agg-first): transform-agg -> GEMM3 (+fused BN3 partial stats) -> bufCb
    k_agg_tr<<<AGB, 256, 0, stream>>>(bufBb, dinv, rowv, colv, bufAb, N, scale, shift);
    k_gemm_mfma<<<gemm3_g, 256, 0, stream>>>(nullptr, bufAb, WT3, bufCb, nullptr,
                                             nullptr, nullptr, nullptr,
                                             part, RT1, 256, N, 64, 256);
    k_bnstat2<<<1, 1024, 0, stream>>>(part, g3, be3, scale, shift, RT1, 256, 1.0f / N);

    k_final_bf<<<2048, 256, 0, stream>>>(bufCb, x, out, scale, shift, N);
}

// Round 10
// 209.005 us; speedup vs baseline: 1.4074x; 1.3465x over previous
//
#include <hip/hip_runtime.h>
#include <hip/hip_bf16.h>

#define BN_EPS 1e-5f
#define CB_SHIFT 9            // 512 nodes per coarse bucket
#define CB_NODES 512
#define CAP 32768             // padded per-bucket capacity (E/ncb ~ 8k; 4x headroom)
#define P1_CHUNK 2048
#define AGB 512               // agg blocks (grid-stride)

typedef __attribute__((ext_vector_type(8))) short short8;
typedef __attribute__((ext_vector_type(4))) float f32x4;

__device__ __forceinline__ ushort f2bf(float x) {
    uint u = __float_as_uint(x);
    u += 0x7FFF + ((u >> 16) & 1);      // round-to-nearest-even
    return (ushort)(u >> 16);
}
__device__ __forceinline__ float bf2f(uint h) { return __uint_as_float(h << 16); }

__device__ __forceinline__ void unpack8(uint4 u, float* v) {
    v[0] = bf2f(u.x & 0xffffu); v[1] = bf2f(u.x >> 16);
    v[2] = bf2f(u.y & 0xffffu); v[3] = bf2f(u.y >> 16);
    v[4] = bf2f(u.z & 0xffffu); v[5] = bf2f(u.z >> 16);
    v[6] = bf2f(u.w & 0xffffu); v[7] = bf2f(u.w >> 16);
}

// ---------------- weight pre-transpose: WT[out][K] bf16 ----------------

__global__ __launch_bounds__(256) void k_prepw(const float* __restrict__ W1,
                                               const float* __restrict__ W2,
                                               const float* __restrict__ W3,
                                               ushort* __restrict__ WT1,
                                               ushort* __restrict__ WT2,
                                               ushort* __restrict__ WT3) {
    int b = blockIdx.x;
    const float* src; ushort* dst; int K, OUT, out;
    if (b < 64)       { out = b;       K = 256; OUT = 64;  src = W1; dst = WT1; }
    else if (b < 128) { out = b - 64;  K = 64;  OUT = 64;  src = W2; dst = WT2; }
    else              { out = b - 128; K = 64;  OUT = 256; src = W3; dst = WT3; }
    for (int k = threadIdx.x; k < K; k += 256)
        dst[(size_t)out * K + k] = f2bf(src[(size_t)k * OUT + out]);
}

// ---------------- CSR build: fixed-capacity buckets ----------------
// pass 1: scatter edges into bucket-padded key array. key = (dst_local<<17)|src (N<=131072)

__global__ __launch_bounds__(256) void k_p1(const int* __restrict__ src,
                                            const int* __restrict__ dst,
                                            int* __restrict__ claim,
                                            uint* __restrict__ keys, int E) {
    __shared__ int hist[128];
    __shared__ int wpos[128];
    int tid = threadIdx.x;
    int c0 = blockIdx.x * P1_CHUNK;
    if (tid < 128) hist[tid] = 0;
    __syncthreads();
    for (int i = tid; i < P1_CHUNK; i += 256) {
        int e = c0 + i;
        if (e < E) atomicAdd(&hist[dst[e] >> CB_SHIFT], 1);
    }
    __syncthreads();
    if (tid < 128) wpos[tid] = hist[tid] ? atomicAdd(&claim[tid], hist[tid]) : 0;
    __syncthreads();
    for (int i = tid; i < P1_CHUNK; i += 256) {
        int e = c0 + i;
        if (e < E) {
            int d = dst[e];
            int b = d >> CB_SHIFT;
            uint key = ((uint)(d & (CB_NODES - 1)) << 17) | (uint)src[e];
            int slot = atomicAdd(&wpos[b], 1);
            keys[(size_t)b * CAP + slot] = key;
        }
    }
}

// pass 2 per bucket: LDS hist -> local scan -> row{beg,deg}/dinv -> scatter col (padded space)

__global__ __launch_bounds__(256) void k_build(const uint* __restrict__ keys,
                                               const int* __restrict__ claim,
                                               int2* __restrict__ row,
                                               float* __restrict__ dinv,
                                               int* __restrict__ col, int n) {
    __shared__ int hist[CB_NODES];
    __shared__ int excl[CB_NODES];
    __shared__ int lpos[CB_NODES];
    __shared__ int ps[256];
    int t = threadIdx.x;
    int cb = blockIdx.x;
    int cnt = claim[cb];
    const uint* kb = keys + (size_t)cb * CAP;
    int base = cb * CAP;
    for (int i = t; i < CB_NODES; i += 256) { hist[i] = 0; lpos[i] = 0; }
    __syncthreads();
    for (int j = t; j < cnt; j += 256) atomicAdd(&hist[kb[j] >> 17], 1);
    __syncthreads();
    ps[t] = hist[2 * t] + hist[2 * t + 1];
    __syncthreads();
    for (int off = 1; off < 256; off <<= 1) {
        int v = ps[t];
        int a = (t >= off) ? ps[t - off] : 0;
        __syncthreads();
        ps[t] = v + a;
        __syncthreads();
    }
    int b0 = (t == 0) ? 0 : ps[t - 1];
    excl[2 * t] = b0;
    excl[2 * t + 1] = b0 + hist[2 * t];
    __syncthreads();
    for (int i = t; i < CB_NODES; i += 256) {
        int node = (cb << CB_SHIFT) + i;
        if (node < n) {
            row[node] = make_int2(base + excl[i], hist[i]);
            dinv[node] = rsqrtf((float)hist[i] + 1.0f);
        }
    }
    __syncthreads();
    for (int j = t; j < cnt; j += 256) {
        uint key = kb[j];
        int nl = key >> 17;
        col[base + excl[nl] + atomicAdd(&lpos[nl], 1)] = (int)(key & 0x1FFFFu);
    }
}

// ---------------- MFMA bf16 GEMM: C[n,OUT] = transform(A[n,K]) @ W ----------------
// WT is pre-transposed bf16 [OUT][K]. transform (scale!=null): a=relu(a*sc+sh).
// epilogue ×dinv[row] if dinv; optional fused BN partial stats (part!=null):
// part[bx*OUTW + col] = per-block row-sum, part[(nblk+bx)*OUTW + col] = sumsq.

__global__ __launch_bounds__(256) void k_gemm_mfma(
    const float* __restrict__ Af, const ushort* __restrict__ Ab,
    const ushort* __restrict__ WT,
    ushort* __restrict__ Cb, float* __restrict__ Cf,
    const float* __restrict__ scale, const float* __restrict__ shift,
    const float* __restrict__ dinv,
    float* __restrict__ part, int nblk, int OUTW,
    int n, int K, int OUT)
{
    __shared__ ushort As[64][40];   // [row][k]
    __shared__ ushort Wt[64][40];   // [col][k]
    __shared__ float ssum[64][17];
    __shared__ float ssq[64][17];
    const int row0 = blockIdx.x * 64;
    const int col0 = blockIdx.y * 64;
    const int tid = threadIdx.x;
    const int wv = tid >> 6;
    const int lane = tid & 63;
    const int fr = lane & 15;
    const int kb = lane >> 4;

    const int ar  = tid >> 2;         // A stage: row 0..63
    const int akc = (tid & 3) << 3;   // A stage: k offset 0,8,16,24
    const int wc  = tid >> 2;         // W stage: col 0..63
    const int wkc = (tid & 3) << 3;   // W stage: k offset

    f32x4 acc[4];
    acc[0] = acc[1] = acc[2] = acc[3] = (f32x4){0.f, 0.f, 0.f, 0.f};

    for (int k0 = 0; k0 < K; k0 += 32) {
        int gr = row0 + ar;
        if (Af) {
            float v[8];
            if (gr < n) {
                const float* ap = Af + (size_t)gr * K + k0 + akc;
                float4 x0 = *(const float4*)ap;
                float4 x1 = *(const float4*)(ap + 4);
                v[0] = x0.x; v[1] = x0.y; v[2] = x0.z; v[3] = x0.w;
                v[4] = x1.x; v[5] = x1.y; v[6] = x1.z; v[7] = x1.w;
            } else {
                #pragma unroll
                for (int j = 0; j < 8; ++j) v[j] = 0.f;
            }
            uint4 w;
            w.x = (uint)f2bf(v[0]) | ((uint)f2bf(v[1]) << 16);
            w.y = (uint)f2bf(v[2]) | ((uint)f2bf(v[3]) << 16);
            w.z = (uint)f2bf(v[4]) | ((uint)f2bf(v[5]) << 16);
            w.w = (uint)f2bf(v[6]) | ((uint)f2bf(v[7]) << 16);
            *(uint4*)&As[ar][akc] = w;
        } else if (scale) {
            float v[8];
            if (gr < n) {
                uint4 u = *(const uint4*)(Ab + (size_t)gr * K + k0 + akc);
                unpack8(u, v);
                #pragma unroll
                for (int j = 0; j < 8; ++j)
                    v[j] = fmaxf(v[j] * scale[k0 + akc + j] + shift[k0 + akc + j], 0.f);
            } else {
                #pragma unroll
                for (int j = 0; j < 8; ++j) v[j] = 0.f;
            }
            uint4 w;
            w.x = (uint)f2bf(v[0]) | ((uint)f2bf(v[1]) << 16);
            w.y = (uint)f2bf(v[2]) | ((uint)f2bf(v[3]) << 16);
            w.z = (uint)f2bf(v[4]) | ((uint)f2bf(v[5]) << 16);
            w.w = (uint)f2bf(v[6]) | ((uint)f2bf(v[7]) << 16);
            *(uint4*)&As[ar][akc] = w;
        } else {
            uint4 u = make_uint4(0, 0, 0, 0);
            if (gr < n) u = *(const uint4*)(Ab + (size_t)gr * K + k0 + akc);
            *(uint4*)&As[ar][akc] = u;
        }
        // W stage: vector copy from pre-transposed WT
        {
            uint4 u = *(const uint4*)(WT + (size_t)(col0 + wc) * K + k0 + wkc);
            *(uint4*)&Wt[wc][wkc] = u;
        }
        __syncthreads();
        short8 a = *(const short8*)&As[16 * wv + fr][kb << 3];
        #pragma unroll
        for (int ct = 0; ct < 4; ++ct) {
            short8 b = *(const short8*)&Wt[ct * 16 + fr][kb << 3];
            acc[ct] = __builtin_amdgcn_mfma_f32_16x16x32_bf16(a, b, acc[ct], 0, 0, 0);
        }
        __syncthreads();
    }

    // epilogue: D row = 16*wv + kb*4 + r, col = ct*16 + fr
    const int contrib = wv * 4 + kb;   // 0..15
    #pragma unroll
    for (int ct = 0; ct < 4; ++ct) {
        float psum = 0.f, psq = 0.f;
        #pragma unroll
        for (int r = 0; r < 4; ++r) {
            int gr = row0 + 16 * wv + (kb << 2) + r;
            if (gr >= n) continue;
            float dv = dinv ? dinv[gr] : 1.0f;
            float val = acc[ct][r] * dv;
            int gc = col0 + ct * 16 + fr;
            if (Cb) Cb[(size_t)gr * OUT + gc] = f2bf(val);
            else    Cf[(size_t)gr * OUT + gc] = val;
            psum += val;
            psq += val * val;
        }
        if (part) {
            ssum[ct * 16 + fr][contrib] = psum;
            ssq[ct * 16 + fr][contrib] = psq;
        }
    }
    if (part) {
        __syncthreads();
        if (tid < 64) {
            float s = 0.f, s2 = 0.f;
            #pragma unroll
            for (int i = 0; i < 16; ++i) { s += ssum[tid][i]; s2 += ssq[tid][i]; }
            part[(size_t)blockIdx.x * OUTW + col0 + tid] = s;
            part[(size_t)(nblk + blockIdx.x) * OUTW + col0 + tid] = s2;
        }
    }
}

// ---------------- aggregation + fused BN partial stats (conv1/conv2) ----------------
// out[i] = dinv[i] * (Hs[i] + sum_{src} Hs[src]); grid-stride, 32 nodes/block-iter.

__global__ __launch_bounds__(256) void k_agg_st(
    const ushort* __restrict__ Hs, const float* __restrict__ dinv,
    const int2* __restrict__ row, const int* __restrict__ col,
    ushort* __restrict__ outp, float* __restrict__ part, int n, int nblk)
{
    int tid = threadIdx.x;
    int sub = (tid & 63) >> 3;
    int wvb = tid >> 6;                 // wave in block 0..3
    int cg = (tid & 7) << 3;
    int nch = (n + 31) >> 5;
    float asum[8] = {0.f}, asq[8] = {0.f};
    for (int ch = blockIdx.x; ch < nch; ch += gridDim.x) {
        int node = (ch << 5) + (wvb << 3) + sub;
        if (node >= n) continue;
        float s[8], v[8];
        uint4 u = *(const uint4*)(Hs + (size_t)node * 64 + cg);
        unpack8(u, s);
        int2 rd = row[node];
        int b = rd.x, deg = rd.y;
        int j = 0;
        for (; j + 4 <= deg; j += 4) {
            int i0 = col[b + j], i1 = col[b + j + 1], i2 = col[b + j + 2], i3 = col[b + j + 3];
            uint4 u0 = *(const uint4*)(Hs + (size_t)i0 * 64 + cg);
            uint4 u1 = *(const uint4*)(Hs + (size_t)i1 * 64 + cg);
            uint4 u2 = *(const uint4*)(Hs + (size_t)i2 * 64 + cg);
            uint4 u3 = *(const uint4*)(Hs + (size_t)i3 * 64 + cg);
            unpack8(u0, v);
            #pragma unroll
            for (int q = 0; q < 8; ++q) s[q] += v[q];
            unpack8(u1, v);
            #pragma unroll
            for (int q = 0; q < 8; ++q) s[q] += v[q];
            unpack8(u2, v);
            #pragma unroll
            for (int q = 0; q < 8; ++q) s[q] += v[q];
            unpack8(u3, v);
            #pragma unroll
            for (int q = 0; q < 8; ++q) s[q] += v[q];
        }
        for (; j < deg; ++j) {
            uint4 u0 = *(const uint4*)(Hs + (size_t)col[b + j] * 64 + cg);
            unpack8(u0, v);
            #pragma unroll
            for (int q = 0; q < 8; ++q) s[q] += v[q];
        }
        float dn = dinv[node];
        uint4 w;
        float o[8];
        #pragma unroll
        for (int q = 0; q < 8; ++q) {
            o[q] = s[q] * dn;
            asum[q] += o[q];
            asq[q] += o[q] * o[q];
        }
        w.x = (uint)f2bf(o[0]) | ((uint)f2bf(o[1]) << 16);
        w.y = (uint)f2bf(o[2]) | ((uint)f2bf(o[3]) << 16);
        w.z = (uint)f2bf(o[4]) | ((uint)f2bf(o[5]) << 16);
        w.w = (uint)f2bf(o[6]) | ((uint)f2bf(o[7]) << 16);
        *(uint4*)(outp + (size_t)node * 64 + cg) = w;
    }
    __shared__ float ls[256][8];
    __shared__ float ls2[256][8];
    #pragma unroll
    for (int q = 0; q < 8; ++q) { ls[tid][q] = asum[q]; ls2[tid][q] = asq[q]; }
    __syncthreads();
    for (int off = 128; off >= 8; off >>= 1) {
        if (tid < off) {
            #pragma unroll
            for (int q = 0; q < 8; ++q) {
                ls[tid][q] += ls[tid + off][q];
                ls2[tid][q] += ls2[tid + off][q];
            }
        }
        __syncthreads();
    }
    if (tid < 8) {
        #pragma unroll
        for (int q = 0; q < 8; ++q) {
            part[(size_t)blockIdx.x * 64 + tid * 8 + q] = ls[tid][q];
            part[(size_t)(nblk + blockIdx.x) * 64 + tid * 8 + q] = ls2[tid][q];
        }
    }
}

// ---------------- aggregation with fused BN2+ReLU+dinv transform (conv3) ----------------

__global__ __launch_bounds__(256) void k_agg_tr(
    const ushort* __restrict__ Hs, const float* __restrict__ dinv,
    const int2* __restrict__ row, const int* __restrict__ col,
    ushort* __restrict__ outp, int n,
    const float* __restrict__ scale, const float* __restrict__ shift)
{
    int tid = threadIdx.x;
    int sub = (tid & 63) >> 3;
    int wvb = tid >> 6;
    int cg = (tid & 7) << 3;
    float sc[8], sh[8];
    #pragma unroll
    for (int q = 0; q < 8; ++q) { sc[q] = scale[cg + q]; sh[q] = shift[cg + q]; }
    int nch = (n + 31) >> 5;
    for (int ch = blockIdx.x; ch < nch; ch += gridDim.x) {
        int node = (ch << 5) + (wvb << 3) + sub;
        if (node >= n) continue;
        float s[8], v[8];
        {
            uint4 u = *(const uint4*)(Hs + (size_t)node * 64 + cg);
            unpack8(u, v);
            float dv = dinv[node];
            #pragma unroll
            for (int q = 0; q < 8; ++q) s[q] = fmaxf(v[q] * sc[q] + sh[q], 0.f) * dv;
        }
        int2 rd = row[node];
        int b = rd.x, deg = rd.y;
        int j = 0;
        for (; j + 4 <= deg; j += 4) {
            int i0 = col[b + j], i1 = col[b + j + 1], i2 = col[b + j + 2], i3 = col[b + j + 3];
            float d0 = dinv[i0], d1 = dinv[i1], d2 = dinv[i2], d3 = dinv[i3];
            uint4 u0 = *(const uint4*)(Hs + (size_t)i0 * 64 + cg);
            uint4 u1 = *(const uint4*)(Hs + (size_t)i1 * 64 + cg);
            uint4 u2 = *(const uint4*)(Hs + (size_t)i2 * 64 + cg);
            uint4 u3 = *(const uint4*)(Hs + (size_t)i3 * 64 + cg);
            unpack8(u0, v);
            #pragma unroll
            for (int q = 0; q < 8; ++q) s[q] += fmaxf(v[q] * sc[q] + sh[q], 0.f) * d0;
            unpack8(u1, v);
            #pragma unroll
            for (int q = 0; q < 8; ++q) s[q] += fmaxf(v[q] * sc[q] + sh[q], 0.f) * d1;
            unpack8(u2, v);
            #pragma unroll
            for (int q = 0; q < 8; ++q) s[q] += fmaxf(v[q] * sc[q] + sh[q], 0.f) * d2;
            unpack8(u3, v);
            #pragma unroll
            for (int q = 0; q < 8; ++q) s[q] += fmaxf(v[q] * sc[q] + sh[q], 0.f) * d3;
        }
        for (; j < deg; ++j) {
            int i0 = col[b + j];
            float d0 = dinv[i0];
            uint4 u0 = *(const uint4*)(Hs + (size_t)i0 * 64 + cg);
            unpack8(u0, v);
            #pragma unroll
            for (int q = 0; q < 8; ++q) s[q] += fmaxf(v[q] * sc[q] + sh[q], 0.f) * d0;
        }
        float dn = dinv[node];
        uint4 w;
        w.x = (uint)f2bf(s[0] * dn) | ((uint)f2bf(s[1] * dn) << 16);
        w.y = (uint)f2bf(s[2] * dn) | ((uint)f2bf(s[3] * dn) << 16);
        w.z = (uint)f2bf(s[4] * dn) | ((uint)f2bf(s[5] * dn) << 16);
        w.w = (uint)f2bf(s[6] * dn) | ((uint)f2bf(s[7] * dn) << 16);
        *(uint4*)(outp + (size_t)node * 64 + cg) = w;
    }
}

// ---------------- BN stat finalize: one block per channel ----------------

__global__ __launch_bounds__(256) void k_bnstat2(const float* __restrict__ part,
                                                 const float* __restrict__ g,
                                                 const float* __restrict__ be,
                                                 float* __restrict__ scale,
                                                 float* __restrict__ shift,
                                                 int nblk, int W, float inv_n) {
    int c = blockIdx.x;          // channel
    int t = threadIdx.x;
    float s = 0.f, s2 = 0.f;
    for (int b = t; b < nblk; b += 256) {
        s  += part[(size_t)b * W + c];
        s2 += part[(size_t)(nblk + b) * W + c];
    }
    __shared__ float ls[256], ls2[256];
    ls[t] = s;
    ls2[t] = s2;
    __syncthreads();
    for (int off = 128; off > 0; off >>= 1) {
        if (t < off) {
            ls[t] += ls[t + off];
            ls2[t] += ls2[t + off];
        }
        __syncthreads();
    }
    if (t == 0) {
        float m = ls[0] * inv_n;
        float v = ls2[0] * inv_n - m * m;
        float sc = g[c] * rsqrtf(v + BN_EPS);
        scale[c] = sc;
        shift[c] = be[c] - m * sc;
    }
}

// ---------------- final: out = relu(h*scale[c] + shift[c] + x), h bf16, W=256 ----------------

__global__ void k_final_bf(const ushort* __restrict__ h, const float* __restrict__ x,
                           float* __restrict__ out,
                           const float* __restrict__ scale, const float* __restrict__ shift, int n) {
    int idx = blockIdx.x * blockDim.x + threadIdx.x;
    int total = n * 32;
    for (int i = idx; i < total; i += gridDim.x * blockDim.x) {
        int row = i >> 5;
        int c8 = (i & 31) << 3;
        uint4 u = *(const uint4*)(h + (size_t)row * 256 + c8);
        float v[8];
        unpack8(u, v);
        const float* xp = x + (size_t)row * 256 + c8;
        float4 x0 = *(const float4*)xp;
        float4 x1 = *(const float4*)(xp + 4);
        float xv[8] = {x0.x, x0.y, x0.z, x0.w, x1.x, x1.y, x1.z, x1.w};
        float o[8];
        #pragma unroll
        for (int j = 0; j < 8; ++j)
            o[j] = fmaxf(v[j] * scale[c8 + j] + shift[c8 + j] + xv[j], 0.f);
        float* op = out + (size_t)row * 256 + c8;
        *(float4*)op = make_float4(o[0], o[1], o[2], o[3]);
        *(float4*)(op + 4) = make_float4(o[4], o[5], o[6], o[7]);
    }
}

// ---------------- launch ----------------

extern "C" void kernel_launch(void* const* d_in, const int* in_sizes, int n_in,
                              void* d_out, int out_size, void* d_ws, size_t ws_size,
                              hipStream_t stream) {
    const float* x   = (const float*)d_in[0];
    const int*   ei  = (const int*)d_in[1];
    const int    N   = in_sizes[2];
    const int    E   = in_sizes[1] / 2;
    const float* W1  = (const float*)d_in[3];
    const float* g1  = (const float*)d_in[5];
    const float* be1 = (const float*)d_in[6];
    const float* W2  = (const float*)d_in[7];
    const float* g2  = (const float*)d_in[9];
    const float* be2 = (const float*)d_in[10];
    const float* W3  = (const float*)d_in[11];
    const float* g3  = (const float*)d_in[13];
    const float* be3 = (const float*)d_in[14];
    float* out = (float*)d_out;

    char* p = (char*)d_ws;
    auto alloc = [&](size_t bytes) {
        char* q = p;
        p += (bytes + 255) & ~(size_t)255;
        return q;
    };
    const int NCB = (N + CB_NODES - 1) >> CB_SHIFT;
    const int RT1 = (N + 63) / 64;       // gemm row tiles
    size_t part_elems = (size_t)2 * AGB * 64;
    size_t part_elems3 = (size_t)2 * RT1 * 256;
    if (part_elems3 > part_elems) part_elems = part_elems3;

    int*    claim  = (int*)alloc((size_t)NCB * 4);
    int2*   rowv   = (int2*)alloc((size_t)N * 8);
    float*  dinv   = (float*)alloc((size_t)N * 4);
    uint*   keys   = (uint*)alloc((size_t)NCB * CAP * 4);
    int*    colv   = (int*)alloc((size_t)NCB * CAP * 4);
    ushort* WT1    = (ushort*)alloc((size_t)64 * 256 * 2);
    ushort* WT2    = (ushort*)alloc((size_t)64 * 64 * 2);
    ushort* WT3    = (ushort*)alloc((size_t)256 * 64 * 2);
    ushort* bufAb  = (ushort*)alloc((size_t)N * 64 * 2);
    ushort* bufBb  = (ushort*)alloc((size_t)N * 64 * 2);
    ushort* bufCb  = (ushort*)alloc((size_t)N * 256 * 2);
    float*  part   = (float*)alloc(part_elems * 4);
    float*  scale  = (float*)alloc(256 * 4);
    float*  shift  = (float*)alloc(256 * 4);

    const int* srcp = ei;
    const int* dstp = ei + E;

    k_prepw<<<384, 256, 0, stream>>>(W1, W2, W3, WT1, WT2, WT3);
    hipMemsetAsync(claim, 0, (size_t)NCB * 4, stream);
    int p1b = (E + P1_CHUNK - 1) / P1_CHUNK;
    k_p1<<<p1b, 256, 0, stream>>>(srcp, dstp, claim, keys, E);
    k_build<<<NCB, 256, 0, stream>>>(keys, claim, rowv, dinv, colv, N);

    dim3 gemm_g(RT1, 1);
    dim3 gemm3_g(RT1, 4);

    // conv1: A1 = (x @ W1) * dinv (bf16) -> agg+stats -> G1 (pre-BN)
    k_gemm_mfma<<<gemm_g, 256, 0, stream>>>(x, nullptr, WT1, bufAb, nullptr,
                                            nullptr, nullptr, dinv,
                                            nullptr, 0, 0, N, 256, 64);
    k_agg_st<<<AGB, 256, 0, stream>>>(bufAb, dinv, rowv, colv, bufBb, part, N, AGB);
    k_bnstat2<<<64, 256, 0, stream>>>(part, g1, be1, scale, shift, AGB, 64, 1.0f / N);

    // conv2: BN1+ReLU fused into GEMM A-stage; ×dinv epilogue -> agg+stats -> G2 (pre-BN)
    k_gemm_mfma<<<gemm_g, 256, 0, stream>>>(nullptr, bufBb, WT2, bufAb, nullptr,
                                            scale, shift, dinv,
                                            nullptr, 0, 0, N, 64, 64);
    k_agg_st<<<AGB, 256, 0, stream>>>(bufAb, dinv, rowv, colv, bufBb, part, N, AGB);
    k_bnstat2<<<64, 256, 0, stream>>>(part, g2, be2, scale, shift, AGB, 64, 1.0f / N);

    // conv3 (agg-first): transform-agg -> GEMM3 (+fused BN3 partial stats) -> bufCb
    k_agg_tr<<<AGB, 256, 0, stream>>>(bufBb, dinv, rowv, colv, bufAb, N, scale, shift);
    k_gemm_mfma<<<gemm3_g, 256, 0, stream>>>(nullptr, bufAb, WT3, bufCb, nullptr,
                                             nullptr, nullptr, nullptr,
                                             part, RT1, 256, N, 64, 256);
    k_bnstat2<<<256, 256, 0, stream>>>(part, g3, be3, scale, shift, RT1, 256, 1.0f / N);

    k_final_bf<<<2048, 256, 0, stream>>>(bufCb, x, out, scale, shift, N);
}

// Round 11
// 180.806 us; speedup vs baseline: 1.6269x; 1.1560x over previous
//
#include <hip/hip_runtime.h>
#include <hip/hip_bf16.h>

#define BN_EPS 1e-5f
#define CB_SHIFT 9            // 512 nodes per coarse bucket
#define CB_NODES 512
#define CAP 32768             // padded per-bucket capacity (E/ncb ~ 8k; 4x headroom)
#define P1_CHUNK 2048
#define AGB 1024              // agg blocks (grid-stride)

typedef __attribute__((ext_vector_type(8))) short short8;
typedef __attribute__((ext_vector_type(4))) float f32x4;

__device__ __forceinline__ ushort f2bf(float x) {
    uint u = __float_as_uint(x);
    u += 0x7FFF + ((u >> 16) & 1);      // round-to-nearest-even
    return (ushort)(u >> 16);
}
__device__ __forceinline__ float bf2f(uint h) { return __uint_as_float(h << 16); }

__device__ __forceinline__ void unpack8(uint4 u, float* v) {
    v[0] = bf2f(u.x & 0xffffu); v[1] = bf2f(u.x >> 16);
    v[2] = bf2f(u.y & 0xffffu); v[3] = bf2f(u.y >> 16);
    v[4] = bf2f(u.z & 0xffffu); v[5] = bf2f(u.z >> 16);
    v[6] = bf2f(u.w & 0xffffu); v[7] = bf2f(u.w >> 16);
}
__device__ __forceinline__ uint4 pack8(const float* v) {
    uint4 w;
    w.x = (uint)f2bf(v[0]) | ((uint)f2bf(v[1]) << 16);
    w.y = (uint)f2bf(v[2]) | ((uint)f2bf(v[3]) << 16);
    w.z = (uint)f2bf(v[4]) | ((uint)f2bf(v[5]) << 16);
    w.w = (uint)f2bf(v[6]) | ((uint)f2bf(v[7]) << 16);
    return w;
}

// ---------------- weight pre-transpose: WT[out][K] bf16 (also zero-inits claim) ----------------

__global__ __launch_bounds__(256) void k_prepw(const float* __restrict__ W1,
                                               const float* __restrict__ W2,
                                               const float* __restrict__ W3,
                                               ushort* __restrict__ WT1,
                                               ushort* __restrict__ WT2,
                                               ushort* __restrict__ WT3,
                                               int* __restrict__ claim, int ncb) {
    int b = blockIdx.x;
    if (b == 0 && threadIdx.x < ncb) claim[threadIdx.x] = 0;
    const float* src; ushort* dst; int K, OUT, out;
    if (b < 64)       { out = b;       K = 256; OUT = 64;  src = W1; dst = WT1; }
    else if (b < 128) { out = b - 64;  K = 64;  OUT = 64;  src = W2; dst = WT2; }
    else              { out = b - 128; K = 64;  OUT = 256; src = W3; dst = WT3; }
    for (int k = threadIdx.x; k < K; k += 256)
        dst[(size_t)out * K + k] = f2bf(src[(size_t)k * OUT + out]);
}

// ---------------- CSR build: fixed-capacity buckets ----------------
// pass 1: scatter edges into bucket-padded key array. key = (dst_local<<17)|src (N<=131072)

__global__ __launch_bounds__(256) void k_p1(const int* __restrict__ src,
                                            const int* __restrict__ dst,
                                            int* __restrict__ claim,
                                            uint* __restrict__ keys, int E) {
    __shared__ int hist[128];
    __shared__ int wpos[128];
    int tid = threadIdx.x;
    int c0 = blockIdx.x * P1_CHUNK;
    if (tid < 128) hist[tid] = 0;
    __syncthreads();
    for (int i = tid; i < P1_CHUNK; i += 256) {
        int e = c0 + i;
        if (e < E) atomicAdd(&hist[dst[e] >> CB_SHIFT], 1);
    }
    __syncthreads();
    if (tid < 128) wpos[tid] = hist[tid] ? atomicAdd(&claim[tid], hist[tid]) : 0;
    __syncthreads();
    for (int i = tid; i < P1_CHUNK; i += 256) {
        int e = c0 + i;
        if (e < E) {
            int d = dst[e];
            int b = d >> CB_SHIFT;
            uint key = ((uint)(d & (CB_NODES - 1)) << 17) | (uint)src[e];
            int slot = atomicAdd(&wpos[b], 1);
            keys[(size_t)b * CAP + slot] = key;
        }
    }
}

// pass 2 per bucket: LDS hist -> local scan -> row{beg,deg}/dinv -> scatter col (padded space)

__global__ __launch_bounds__(256) void k_build(const uint* __restrict__ keys,
                                               const int* __restrict__ claim,
                                               int2* __restrict__ row,
                                               float* __restrict__ dinv,
                                               int* __restrict__ col, int n) {
    __shared__ int hist[CB_NODES];
    __shared__ int excl[CB_NODES];
    __shared__ int lpos[CB_NODES];
    __shared__ int ps[256];
    int t = threadIdx.x;
    int cb = blockIdx.x;
    int cnt = claim[cb];
    const uint* kb = keys + (size_t)cb * CAP;
    int base = cb * CAP;
    for (int i = t; i < CB_NODES; i += 256) { hist[i] = 0; lpos[i] = 0; }
    __syncthreads();
    for (int j = t; j < cnt; j += 256) atomicAdd(&hist[kb[j] >> 17], 1);
    __syncthreads();
    ps[t] = hist[2 * t] + hist[2 * t + 1];
    __syncthreads();
    for (int off = 1; off < 256; off <<= 1) {
        int v = ps[t];
        int a = (t >= off) ? ps[t - off] : 0;
        __syncthreads();
        ps[t] = v + a;
        __syncthreads();
    }
    int b0 = (t == 0) ? 0 : ps[t - 1];
    excl[2 * t] = b0;
    excl[2 * t + 1] = b0 + hist[2 * t];
    __syncthreads();
    for (int i = t; i < CB_NODES; i += 256) {
        int node = (cb << CB_SHIFT) + i;
        if (node < n) {
            row[node] = make_int2(base + excl[i], hist[i]);
            dinv[node] = rsqrtf((float)hist[i] + 1.0f);
        }
    }
    __syncthreads();
    for (int j = t; j < cnt; j += 256) {
        uint key = kb[j];
        int nl = key >> 17;
        col[base + excl[nl] + atomicAdd(&lpos[nl], 1)] = (int)(key & 0x1FFFFu);
    }
}

// ---------------- MFMA bf16 GEMM (double-buffered): C[n,OUT] = transform(A[n,K]) @ W ----------------
// WT pre-transposed bf16 [OUT][K]. transform (scale!=null): a=relu(a*sc+sh).
// epilogue ×dinv[row] if dinv; optional fused BN partial stats (part!=null).

__global__ __launch_bounds__(256) void k_gemm_mfma(
    const float* __restrict__ Af, const ushort* __restrict__ Ab,
    const ushort* __restrict__ WT,
    ushort* __restrict__ Cb, float* __restrict__ Cf,
    const float* __restrict__ scale, const float* __restrict__ shift,
    const float* __restrict__ dinv,
    float* __restrict__ part, int nblk, int OUTW,
    int n, int K, int OUT)
{
    __shared__ ushort As[2][64][40];   // [buf][row][k]
    __shared__ ushort Wt[2][64][40];   // [buf][col][k]
    __shared__ float ssum[64][17];
    __shared__ float ssq[64][17];
    const int row0 = blockIdx.x * 64;
    const int col0 = blockIdx.y * 64;
    const int tid = threadIdx.x;
    const int wv = tid >> 6;
    const int lane = tid & 63;
    const int fr = lane & 15;
    const int kb = lane >> 4;

    const int ar  = tid >> 2;         // A stage: row 0..63
    const int akc = (tid & 3) << 3;   // A stage: k offset 0,8,16,24
    const int wc  = tid >> 2;         // W stage: col 0..63
    const int wkc = (tid & 3) << 3;   // W stage: k offset
    const int NT = K >> 5;

    f32x4 acc[4];
    acc[0] = acc[1] = acc[2] = acc[3] = (f32x4){0.f, 0.f, 0.f, 0.f};

    uint4 apack, wpack;

#define PREFETCH(k0)                                                                \
    {                                                                               \
        int gr = row0 + ar;                                                         \
        if (Af) {                                                                   \
            float v[8];                                                             \
            if (gr < n) {                                                           \
                const float* ap = Af + (size_t)gr * K + (k0) + akc;                 \
                float4 x0 = *(const float4*)ap;                                     \
                float4 x1 = *(const float4*)(ap + 4);                               \
                v[0] = x0.x; v[1] = x0.y; v[2] = x0.z; v[3] = x0.w;                 \
                v[4] = x1.x; v[5] = x1.y; v[6] = x1.z; v[7] = x1.w;                 \
            } else {                                                                \
                _Pragma("unroll") for (int j = 0; j < 8; ++j) v[j] = 0.f;           \
            }                                                                       \
            apack = pack8(v);                                                       \
        } else if (scale) {                                                         \
            float v[8];                                                             \
            if (gr < n) {                                                           \
                uint4 u = *(const uint4*)(Ab + (size_t)gr * K + (k0) + akc);        \
                unpack8(u, v);                                                      \
                _Pragma("unroll")                                                   \
                for (int j = 0; j < 8; ++j)                                         \
                    v[j] = fmaxf(v[j] * scale[(k0) + akc + j]                       \
                                 + shift[(k0) + akc + j], 0.f);                     \
            } else {                                                                \
                _Pragma("unroll") for (int j = 0; j < 8; ++j) v[j] = 0.f;           \
            }                                                                       \
            apack = pack8(v);                                                       \
        } else {                                                                    \
            apack = make_uint4(0, 0, 0, 0);                                         \
            if (gr < n) apack = *(const uint4*)(Ab + (size_t)gr * K + (k0) + akc);  \
        }                                                                           \
        wpack = *(const uint4*)(WT + (size_t)(col0 + wc) * K + (k0) + wkc);         \
    }

#define STORE(b)                                  \
    {                                             \
        *(uint4*)&As[b][ar][akc] = apack;         \
        *(uint4*)&Wt[b][wc][wkc] = wpack;         \
    }

    PREFETCH(0)
    STORE(0)
    __syncthreads();

    for (int t = 0; t < NT; ++t) {
        int buf = t & 1;
        if (t + 1 < NT) PREFETCH((t + 1) << 5)
        short8 a = *(const short8*)&As[buf][16 * wv + fr][kb << 3];
        #pragma unroll
        for (int ct = 0; ct < 4; ++ct) {
            short8 b = *(const short8*)&Wt[buf][ct * 16 + fr][kb << 3];
            acc[ct] = __builtin_amdgcn_mfma_f32_16x16x32_bf16(a, b, acc[ct], 0, 0, 0);
        }
        if (t + 1 < NT) {
            STORE(buf ^ 1)
            __syncthreads();
        }
    }
#undef PREFETCH
#undef STORE

    // epilogue: D row = 16*wv + kb*4 + r, col = ct*16 + fr
    const int contrib = wv * 4 + kb;   // 0..15
    #pragma unroll
    for (int ct = 0; ct < 4; ++ct) {
        float psum = 0.f, psq = 0.f;
        #pragma unroll
        for (int r = 0; r < 4; ++r) {
            int gr = row0 + 16 * wv + (kb << 2) + r;
            if (gr >= n) continue;
            float dv = dinv ? dinv[gr] : 1.0f;
            float val = acc[ct][r] * dv;
            int gc = col0 + ct * 16 + fr;
            if (Cb) Cb[(size_t)gr * OUT + gc] = f2bf(val);
            else    Cf[(size_t)gr * OUT + gc] = val;
            psum += val;
            psq += val * val;
        }
        if (part) {
            ssum[ct * 16 + fr][contrib] = psum;
            ssq[ct * 16 + fr][contrib] = psq;
        }
    }
    if (part) {
        __syncthreads();
        if (tid < 64) {
            float s = 0.f, s2 = 0.f;
            #pragma unroll
            for (int i = 0; i < 16; ++i) { s += ssum[tid][i]; s2 += ssq[tid][i]; }
            part[(size_t)blockIdx.x * OUTW + col0 + tid] = s;
            part[(size_t)(nblk + blockIdx.x) * OUTW + col0 + tid] = s2;
        }
    }
}

// ---------------- aggregation + fused BN partial stats (conv1/conv2) ----------------
// out[i] = dinv[i] * (Hs[i] + sum_{src} Hs[src]); grid-stride, 32 nodes/block-iter.

__global__ __launch_bounds__(256) void k_agg_st(
    const ushort* __restrict__ Hs, const float* __restrict__ dinv,
    const int2* __restrict__ row, const int* __restrict__ col,
    ushort* __restrict__ outp, float* __restrict__ part, int n, int nblk)
{
    int tid = threadIdx.x;
    int sub = (tid & 63) >> 3;
    int wvb = tid >> 6;                 // wave in block 0..3
    int cg = (tid & 7) << 3;
    int nch = (n + 31) >> 5;
    float asum[8] = {0.f}, asq[8] = {0.f};
    for (int ch = blockIdx.x; ch < nch; ch += gridDim.x) {
        int node = (ch << 5) + (wvb << 3) + sub;
        if (node >= n) continue;
        float s[8], v[8];
        uint4 u = *(const uint4*)(Hs + (size_t)node * 64 + cg);
        unpack8(u, s);
        int2 rd = row[node];
        int b = rd.x, deg = rd.y;
        int j = 0;
        for (; j + 4 <= deg; j += 4) {
            int i0 = col[b + j], i1 = col[b + j + 1], i2 = col[b + j + 2], i3 = col[b + j + 3];
            uint4 u0 = *(const uint4*)(Hs + (size_t)i0 * 64 + cg);
            uint4 u1 = *(const uint4*)(Hs + (size_t)i1 * 64 + cg);
            uint4 u2 = *(const uint4*)(Hs + (size_t)i2 * 64 + cg);
            uint4 u3 = *(const uint4*)(Hs + (size_t)i3 * 64 + cg);
            unpack8(u0, v);
            #pragma unroll
            for (int q = 0; q < 8; ++q) s[q] += v[q];
            unpack8(u1, v);
            #pragma unroll
            for (int q = 0; q < 8; ++q) s[q] += v[q];
            unpack8(u2, v);
            #pragma unroll
            for (int q = 0; q < 8; ++q) s[q] += v[q];
            unpack8(u3, v);
            #pragma unroll
            for (int q = 0; q < 8; ++q) s[q] += v[q];
        }
        for (; j < deg; ++j) {
            uint4 u0 = *(const uint4*)(Hs + (size_t)col[b + j] * 64 + cg);
            unpack8(u0, v);
            #pragma unroll
            for (int q = 0; q < 8; ++q) s[q] += v[q];
        }
        float dn = dinv[node];
        float o[8];
        #pragma unroll
        for (int q = 0; q < 8; ++q) {
            o[q] = s[q] * dn;
            asum[q] += o[q];
            asq[q] += o[q] * o[q];
        }
        *(uint4*)(outp + (size_t)node * 64 + cg) = pack8(o);
    }
    __shared__ float ls[256][8];
    __shared__ float ls2[256][8];
    #pragma unroll
    for (int q = 0; q < 8; ++q) { ls[tid][q] = asum[q]; ls2[tid][q] = asq[q]; }
    __syncthreads();
    for (int off = 128; off >= 8; off >>= 1) {
        if (tid < off) {
            #pragma unroll
            for (int q = 0; q < 8; ++q) {
                ls[tid][q] += ls[tid + off][q];
                ls2[tid][q] += ls2[tid + off][q];
            }
        }
        __syncthreads();
    }
    if (tid < 8) {
        #pragma unroll
        for (int q = 0; q < 8; ++q) {
            part[(size_t)blockIdx.x * 64 + tid * 8 + q] = ls[tid][q];
            part[(size_t)(nblk + blockIdx.x) * 64 + tid * 8 + q] = ls2[tid][q];
        }
    }
}

// ---------------- aggregation with fused BN2+ReLU+dinv transform (conv3) ----------------

__global__ __launch_bounds__(256) void k_agg_tr(
    const ushort* __restrict__ Hs, const float* __restrict__ dinv,
    const int2* __restrict__ row, const int* __restrict__ col,
    ushort* __restrict__ outp, int n,
    const float* __restrict__ scale, const float* __restrict__ shift)
{
    int tid = threadIdx.x;
    int sub = (tid & 63) >> 3;
    int wvb = tid >> 6;
    int cg = (tid & 7) << 3;
    float sc[8], sh[8];
    #pragma unroll
    for (int q = 0; q < 8; ++q) { sc[q] = scale[cg + q]; sh[q] = shift[cg + q]; }
    int nch = (n + 31) >> 5;
    for (int ch = blockIdx.x; ch < nch; ch += gridDim.x) {
        int node = (ch << 5) + (wvb << 3) + sub;
        if (node >= n) continue;
        float s[8], v[8];
        {
            uint4 u = *(const uint4*)(Hs + (size_t)node * 64 + cg);
            unpack8(u, v);
            float dv = dinv[node];
            #pragma unroll
            for (int q = 0; q < 8; ++q) s[q] = fmaxf(v[q] * sc[q] + sh[q], 0.f) * dv;
        }
        int2 rd = row[node];
        int b = rd.x, deg = rd.y;
        int j = 0;
        for (; j + 4 <= deg; j += 4) {
            int i0 = col[b + j], i1 = col[b + j + 1], i2 = col[b + j + 2], i3 = col[b + j + 3];
            float d0 = dinv[i0], d1 = dinv[i1], d2 = dinv[i2], d3 = dinv[i3];
            uint4 u0 = *(const uint4*)(Hs + (size_t)i0 * 64 + cg);
            uint4 u1 = *(const uint4*)(Hs + (size_t)i1 * 64 + cg);
            uint4 u2 = *(const uint4*)(Hs + (size_t)i2 * 64 + cg);
            uint4 u3 = *(const uint4*)(Hs + (size_t)i3 * 64 + cg);
            unpack8(u0, v);
            #pragma unroll
            for (int q = 0; q < 8; ++q) s[q] += fmaxf(v[q] * sc[q] + sh[q], 0.f) * d0;
            unpack8(u1, v);
            #pragma unroll
            for (int q = 0; q < 8; ++q) s[q] += fmaxf(v[q] * sc[q] + sh[q], 0.f) * d1;
            unpack8(u2, v);
            #pragma unroll
            for (int q = 0; q < 8; ++q) s[q] += fmaxf(v[q] * sc[q] + sh[q], 0.f) * d2;
            unpack8(u3, v);
            #pragma unroll
            for (int q = 0; q < 8; ++q) s[q] += fmaxf(v[q] * sc[q] + sh[q], 0.f) * d3;
        }
        for (; j < deg; ++j) {
            int i0 = col[b + j];
            float d0 = dinv[i0];
            uint4 u0 = *(const uint4*)(Hs + (size_t)i0 * 64 + cg);
            unpack8(u0, v);
            #pragma unroll
            for (int q = 0; q < 8; ++q) s[q] += fmaxf(v[q] * sc[q] + sh[q], 0.f) * d0;
        }
        float dn = dinv[node];
        float o[8];
        #pragma unroll
        for (int q = 0; q < 8; ++q) o[q] = s[q] * dn;
        *(uint4*)(outp + (size_t)node * 64 + cg) = pack8(o);
    }
}

// ---------------- BN stat finalize: one block per channel ----------------

__global__ __launch_bounds__(256) void k_bnstat2(const float* __restrict__ part,
                                                 const float* __restrict__ g,
                                                 const float* __restrict__ be,
                                                 float* __restrict__ scale,
                                                 float* __restrict__ shift,
                                                 int nblk, int W, float inv_n) {
    int c = blockIdx.x;          // channel
    int t = threadIdx.x;
    float s = 0.f, s2 = 0.f;
    for (int b = t; b < nblk; b += 256) {
        s  += part[(size_t)b * W + c];
        s2 += part[(size_t)(nblk + b) * W + c];
    }
    __shared__ float ls[256], ls2[256];
    ls[t] = s;
    ls2[t] = s2;
    __syncthreads();
    for (int off = 128; off > 0; off >>= 1) {
        if (t < off) {
            ls[t] += ls[t + off];
            ls2[t] += ls2[t + off];
        }
        __syncthreads();
    }
    if (t == 0) {
        float m = ls[0] * inv_n;
        float v = ls2[0] * inv_n - m * m;
        float sc = g[c] * rsqrtf(v + BN_EPS);
        scale[c] = sc;
        shift[c] = be[c] - m * sc;
    }
}

// ---------------- final: out = relu(h*scale[c] + shift[c] + x), h bf16, W=256 ----------------

__global__ void k_final_bf(const ushort* __restrict__ h, const float* __restrict__ x,
                           float* __restrict__ out,
                           const float* __restrict__ scale, const float* __restrict__ shift, int n) {
    int idx = blockIdx.x * blockDim.x + threadIdx.x;
    int total = n * 32;
    for (int i = idx; i < total; i += gridDim.x * blockDim.x) {
        int row = i >> 5;
        int c8 = (i & 31) << 3;
        uint4 u = *(const uint4*)(h + (size_t)row * 256 + c8);
        float v[8];
        unpack8(u, v);
        const float* xp = x + (size_t)row * 256 + c8;
        float4 x0 = *(const float4*)xp;
        float4 x1 = *(const float4*)(xp + 4);
        float xv[8] = {x0.x, x0.y, x0.z, x0.w, x1.x, x1.y, x1.z, x1.w};
        float o[8];
        #pragma unroll
        for (int j = 0; j < 8; ++j)
            o[j] = fmaxf(v[j] * scale[c8 + j] + shift[c8 + j] + xv[j], 0.f);
        float* op = out + (size_t)row * 256 + c8;
        *(float4*)op = make_float4(o[0], o[1], o[2], o[3]);
        *(float4*)(op + 4) = make_float4(o[4], o[5], o[6], o[7]);
    }
}

// ---------------- launch ----------------

extern "C" void kernel_launch(void* const* d_in, const int* in_sizes, int n_in,
                              void* d_out, int out_size, void* d_ws, size_t ws_size,
                              hipStream_t stream) {
    const float* x   = (const float*)d_in[0];
    const int*   ei  = (const int*)d_in[1];
    const int    N   = in_sizes[2];
    const int    E   = in_sizes[1] / 2;
    const float* W1  = (const float*)d_in[3];
    const float* g1  = (const float*)d_in[5];
    const float* be1 = (const float*)d_in[6];
    const float* W2  = (const float*)d_in[7];
    const float* g2  = (const float*)d_in[9];
    const float* be2 = (const float*)d_in[10];
    const float* W3  = (const float*)d_in[11];
    const float* g3  = (const float*)d_in[13];
    const float* be3 = (const float*)d_in[14];
    float* out = (float*)d_out;

    char* p = (char*)d_ws;
    auto alloc = [&](size_t bytes) {
        char* q = p;
        p += (bytes + 255) & ~(size_t)255;
        return q;
    };
    const int NCB = (N + CB_NODES - 1) >> CB_SHIFT;
    const int RT1 = (N + 63) / 64;       // gemm row tiles
    size_t part_elems = (size_t)2 * AGB * 64;
    size_t part_elems3 = (size_t)2 * RT1 * 256;
    if (part_elems3 > part_elems) part_elems = part_elems3;

    int*    claim  = (int*)alloc((size_t)NCB * 4);
    int2*   rowv   = (int2*)alloc((size_t)N * 8);
    float*  dinv   = (float*)alloc((size_t)N * 4);
    uint*   keys   = (uint*)alloc((size_t)NCB * CAP * 4);
    int*    colv   = (int*)alloc((size_t)NCB * CAP * 4);
    ushort* WT1    = (ushort*)alloc((size_t)64 * 256 * 2);
    ushort* WT2    = (ushort*)alloc((size_t)64 * 64 * 2);
    ushort* WT3    = (ushort*)alloc((size_t)256 * 64 * 2);
    ushort* bufAb  = (ushort*)alloc((size_t)N * 64 * 2);
    ushort* bufBb  = (ushort*)alloc((size_t)N * 64 * 2);
    ushort* bufCb  = (ushort*)alloc((size_t)N * 256 * 2);
    float*  part   = (float*)alloc(part_elems * 4);
    float*  scale  = (float*)alloc(256 * 4);
    float*  shift  = (float*)alloc(256 * 4);

    const int* srcp = ei;
    const int* dstp = ei + E;

    k_prepw<<<384, 256, 0, stream>>>(W1, W2, W3, WT1, WT2, WT3, claim, NCB);
    int p1b = (E + P1_CHUNK - 1) / P1_CHUNK;
    k_p1<<<p1b, 256, 0, stream>>>(srcp, dstp, claim, keys, E);
    k_build<<<NCB, 256, 0, stream>>>(keys, claim, rowv, dinv, colv, N);

    dim3 gemm_g(RT1, 1);
    dim3 gemm3_g(RT1, 4);

    // conv1: A1 = (x @ W1) * dinv (bf16) -> agg+stats -> G1 (pre-BN)
    k_gemm_mfma<<<gemm_g, 256, 0, stream>>>(x, nullptr, WT1, bufAb, nullptr,
                                            nullptr, nullptr, dinv,
                                            nullptr, 0, 0, N, 256, 64);
    k_agg_st<<<AGB, 256, 0, stream>>>(bufAb, dinv, rowv, colv, bufBb, part, N, AGB);
    k_bnstat2<<<64, 256, 0, stream>>>(part, g1, be1, scale, shift, AGB, 64, 1.0f / N);

    // conv2: BN1+ReLU fused into GEMM A-stage; ×dinv epilogue -> agg+stats -> G2 (pre-BN)
    k_gemm_mfma<<<gemm_g, 256, 0, stream>>>(nullptr, bufBb, WT2, bufAb, nullptr,
                                            scale, shift, dinv,
                                            nullptr, 0, 0, N, 64, 64);
    k_agg_st<<<AGB, 256, 0, stream>>>(bufAb, dinv, rowv, colv, bufBb, part, N, AGB);
    k_bnstat2<<<64, 256, 0, stream>>>(part, g2, be2, scale, shift, AGB, 64, 1.0f / N);

    // conv3 (agg-first): transform-agg -> GEMM3 (+fused BN3 partial stats) -> bufCb
    k_agg_tr<<<AGB, 256, 0, stream>>>(bufBb, dinv, rowv, colv, bufAb, N, scale, shift);
    k_gemm_mfma<<<gemm3_g, 256, 0, stream>>>(nullptr, bufAb, WT3, bufCb, nullptr,
                                             nullptr, nullptr, nullptr,
                                             part, RT1, 256, N, 64, 256);
    k_bnstat2<<<256, 256, 0, stream>>>(part, g3, be3, scale, shift, RT1, 256, 1.0f / N);

    k_final_bf<<<2048, 256, 0, stream>>>(bufCb, x, out, scale, shift, N);
}